// Round 13
// baseline (391.674 us; speedup 1.0000x reference)
//
#include <hip/hip_runtime.h>
#include <math.h>

// Problem constants
#define BB   2
#define TT   2048
#define CC   1024
#define HH   16
#define DD   64
#define HID  256
#define FFD  4096
#define NTOK (BB*TT)        // 4096
#define CT   64             // scan chunk length
#define NC   (TT/CT)        // 32 chunks per sequence
#define NBH  (BB*HH)        // 32 sequences
#define NCHK (NBH*NC)       // 1024 chunk-blocks
#define MB   (1048576ULL)

typedef unsigned short u16;
typedef unsigned int   u32;
typedef __attribute__((ext_vector_type(8))) short frag8;   // 8 bf16 = 4 VGPRs
typedef __attribute__((ext_vector_type(4))) float f32x4;

__device__ __forceinline__ float bf2f(u16 h){
    union { u32 u; float f; } c; c.u = ((u32)h) << 16; return c.f;
}
__device__ __forceinline__ u16 f2bf(float f){
    union { float f; u32 u; } c; c.f = f;
    u32 u = c.u;
    u += 0x7FFFu + ((u >> 16) & 1u);   // RNE
    return (u16)(u >> 16);
}
// idx >= 0: runtime flag (1 = f32). idx == -1: bf16. idx == -2: f32.
__device__ __forceinline__ bool is_f32(const u32* flags, int idx) {
    if (idx == -2) return true;
    if (idx < 0)  return false;
    return flags[idx] != 0;
}

// async 16B global -> LDS (DMA; LDS dest = wave-uniform base + lane*16)
__device__ __forceinline__ void gload16(const void* g, void* l) {
    __builtin_amdgcn_global_load_lds(
        (const __attribute__((address_space(1))) u32*)g,
        (__attribute__((address_space(3))) u32*)l, 16, 0, 0);
}

// counted vmem wait (keeps N loads in flight across barriers)
template<int N> __device__ __forceinline__ void wait_vm() {
    if constexpr (N == 0)      asm volatile("s_waitcnt vmcnt(0)" ::: "memory");
    else if constexpr (N == 4) asm volatile("s_waitcnt vmcnt(4)" ::: "memory");
    else                       asm volatile("s_waitcnt vmcnt(6)" ::: "memory");
}
__device__ __forceinline__ void barrier_raw() {
    asm volatile("s_barrier" ::: "memory");     // NO implicit waitcnt drain
}

// ---------------------------------------------------------------------------
// dtype sniffer (unchanged)
// ---------------------------------------------------------------------------
struct InPtrs { const void* p[11]; int n[11]; };

__global__ __launch_bounds__(64)
void sniff_kernel(InPtrs ip, u32* __restrict__ flags)
{
    int lane = threadIdx.x;
    u32 f0 = 0;
    for (int i = 0; i < 11; i++) {
        const u16* p = (const u16*)ip.p[i];
        int cap = ip.n[i] < 256 ? ip.n[i] : 256;
        bool ok = true;
        for (int j = lane; j < cap; j += 64) {
            u16 u = p[j];
            u32 e = (u >> 7) & 0xFFu;
            bool good = (u == 0u) || (u == 0x8000u) || (e >= 64u && e < 192u);
            ok = ok && good;
        }
        unsigned long long ball = __ballot(ok);
        u32 fl = (ball == ~0ull) ? 0u : 1u;
        if (ip.n[i] < 64) fl = f0;       // tiny tensors inherit x's dtype
        if (i == 0) f0 = fl;
        if (lane == 0) flags[i] = fl;
    }
}

// ---------------------------------------------------------------------------
// bf16 pre-conversion (unchanged)
// ---------------------------------------------------------------------------
struct ConvArgs {
    const void* src[6];
    u16* dst[6];
    int flag[6];
    int bstart[7];
    int nseg;
};

__global__ __launch_bounds__(256)
void conv_kernel(ConvArgs a, const u32* __restrict__ flags)
{
    int b = blockIdx.x;
    int s = 0;
    #pragma unroll
    for (int i = 1; i < 6; i++) if (i < a.nseg && b >= a.bstart[i]) s = i;
    size_t off = ((size_t)(b - a.bstart[s])) * 2048 + (size_t)threadIdx.x * 8;
    u16* d = a.dst[s] + off;
    if (flags[a.flag[s]] != 0) {
        const float* sp = (const float*)a.src[s] + off;
        float4 x0 = *(const float4*)sp;
        float4 x1 = *(const float4*)(sp + 4);
        u16 buf[8];
        buf[0]=f2bf(x0.x); buf[1]=f2bf(x0.y); buf[2]=f2bf(x0.z); buf[3]=f2bf(x0.w);
        buf[4]=f2bf(x1.x); buf[5]=f2bf(x1.y); buf[6]=f2bf(x1.z); buf[7]=f2bf(x1.w);
        *(uint4*)d = *(uint4*)buf;
    } else {
        *(uint4*)d = *(const uint4*)((const u16*)a.src[s] + off);
    }
}

// XCD-aware block remap (unchanged): pure permutation, NB % 8 == 0.
__device__ __forceinline__ void xcd_map(int i, int NB, int gx, int& bm, int& bn)
{
    int per = NB >> 3;
    int iq  = (i & 7) * per + (i >> 3);
    bm = iq / gx;
    bn = iq % gx;
}

// ---------------------------------------------------------------------------
// NT GEMM, MFMA core, bf16 inputs, global_load_lds staging with 2-buffer
// pipeline (R6-proven best). BK = KS*32 as KS separate [rows][32] sub-tiles.
// MODE: 0 plain f32 partial (z ? Cm2 : Cm), 2 relu^2 -> bf16,
// 3 +residual(aux) -> Cm (dtype by oi).
// ---------------------------------------------------------------------------
template<int MODE, int BM, int BN, int KS>
__global__ __launch_bounds__(256)
void gemm_nt(const u16* __restrict__ A, const u16* __restrict__ B,
             void* Cm, void* Cm2, const void* aux,
             int M, int N, int K, int lda, int ldb,
             const u32* __restrict__ flags, int oi)
{
    constexpr int MFR = BM / 32;
    constexpr int NFR = BN / 32;
    constexpr int BKE = KS * 32;
    const bool of32 = is_f32(flags, oi);
    __shared__ u16 As[2][KS][BM * 32];
    __shared__ u16 Bs[2][KS][BN * 32];
    const int tid = threadIdx.x;
    int bm, bn;
    xcd_map(blockIdx.x, gridDim.x, N / BN, bm, bn);
    const int z = blockIdx.y;
    const size_t koff = (size_t)z * K;

    const int wave = tid >> 6, lane = tid & 63;
    const int lm = lane & 15, quad = lane >> 4;
    const int wm = (wave >> 1) * (BM / 2), wn = (wave & 1) * (BN / 2);

    const int srow = lane >> 2;           // 0..15
    const int scol = (lane & 3) * 8;      // 0,8,16,24
    const int arow = (BM == 128) ? (wave*32 + srow) : (wave*16 + srow);
    const int brow = (BN == 128) ? (wave*32 + srow) : (wave*16 + srow);
    const u16* gA = A + (size_t)(bm*BM + arow)*lda + koff + scol;
    const u16* gB = B + (size_t)(bn*BN + brow)*ldb + koff + scol;
    const size_t a16 = (size_t)16 * lda, b16 = (size_t)16 * ldb;

    f32x4 acc[MFR][NFR];
    #pragma unroll
    for (int i = 0; i < MFR; i++)
        #pragma unroll
        for (int j = 0; j < NFR; j++)
            acc[i][j] = (f32x4){0.f, 0.f, 0.f, 0.f};

    auto stage = [&](int buf, int kk) {
        #pragma unroll
        for (int ks = 0; ks < KS; ks++) {
            if constexpr (BM == 128) {
                gload16(gA + kk + ks*32,       &As[buf][ks][wave*1024]);
                gload16(gA + kk + ks*32 + a16, &As[buf][ks][wave*1024 + 512]);
            } else {
                gload16(gA + kk + ks*32, &As[buf][ks][wave*512]);
            }
            if constexpr (BN == 128) {
                gload16(gB + kk + ks*32,       &Bs[buf][ks][wave*1024]);
                gload16(gB + kk + ks*32 + b16, &Bs[buf][ks][wave*1024 + 512]);
            } else {
                gload16(gB + kk + ks*32, &Bs[buf][ks][wave*512]);
            }
        }
    };

    stage(0, 0);
    __syncthreads();                       // buf0 DMA landed
    int cur = 0;
    for (int k0 = 0; k0 < K; k0 += BKE) {
        if (k0 + BKE < K) stage(cur ^ 1, k0 + BKE);  // prefetch next tile
        #pragma unroll
        for (int ks = 0; ks < KS; ks++) {
            frag8 af[MFR], bfr[NFR];
            #pragma unroll
            for (int i = 0; i < MFR; i++)
                af[i]  = *(frag8*)&As[cur][ks][(wm + i*16 + lm)*32 + quad*8];
            #pragma unroll
            for (int j = 0; j < NFR; j++)
                bfr[j] = *(frag8*)&Bs[cur][ks][(wn + j*16 + lm)*32 + quad*8];
            #pragma unroll
            for (int i = 0; i < MFR; i++)
                #pragma unroll
                for (int j = 0; j < NFR; j++)
                    acc[i][j] = __builtin_amdgcn_mfma_f32_16x16x32_bf16(
                        af[i], bfr[j], acc[i][j], 0, 0, 0);
        }
        __syncthreads();                   // next-tile DMA landed; reads done
        cur ^= 1;
    }

    float* outF = (float*)(z ? Cm2 : Cm);
    // C/D map (m89/m91): col = lane&15, row = quad*4 + reg
    #pragma unroll
    for (int i = 0; i < MFR; i++) {
        #pragma unroll
        for (int j = 0; j < NFR; j++) {
            const int gcol = bn*BN + wn + j*16 + lm;
            #pragma unroll
            for (int r = 0; r < 4; r++) {
                const int grow = bm*BM + wm + i*16 + quad*4 + r;
                size_t off = (size_t)grow * N + gcol;
                float vv = acc[i][j][r];
                if constexpr (MODE == 0) {
                    outF[off] = vv;
                } else if constexpr (MODE == 2) {
                    vv = fmaxf(vv, 0.f);
                    ((u16*)Cm)[off] = f2bf(vv * vv);
                } else { // MODE 3: residual add, dtype-matched output
                    float res = of32 ? ((const float*)aux)[off]
                                     : bf2f(((const u16*)aux)[off]);
                    vv += res;
                    if (of32) ((float*)Cm)[off] = vv;
                    else      ((u16*)Cm)[off]   = f2bf(vv);
                }
            }
        }
    }
}

// ---------------------------------------------------------------------------
// fc GEMM, 8-wave 256x256 phase-split schedule with counted vmcnt (T3+T4,
// linear LDS): h1 = relu(yn @ Wfc^T)^2. M=N=4096, K=1024, lda=ldb=1024.
// Per K-tile (BK=64): 4 phases, each = {issue 1 half-tile prefetch (2 gloads)
// -> own-wave vmcnt(N) -> s_barrier -> ds_read quadrant -> setprio+16 MFMA}.
// Waits: ph0 vmcnt(6), ph1 vmcnt(4) (last tile: 4/0), ph2/3 none — loads get
// 3-4 phases of flight. Race-audit: a half staged at t+1-ph_p was last read
// at t-ph<=3 with >=1 intervening barrier; K-accum order identical to the
// 2-phase kernel (bit-identical output).
// ---------------------------------------------------------------------------
__global__ __launch_bounds__(512)
void gemm_fc8(const u16* __restrict__ A, const u16* __restrict__ B,
              u16* __restrict__ C)
{
    __shared__ u16 As[2][256 * 64];
    __shared__ u16 Bs[2][256 * 64];
    const int tid = threadIdx.x;
    int bm, bn;
    xcd_map(blockIdx.x, 256, 16, bm, bn);

    const int w = tid >> 6, lane = tid & 63;
    const int lm = lane & 15, quad = lane >> 4;
    const int wm = (w >> 2) * 128, wn = (w & 3) * 64;

    // staging: thread covers row tid>>3 (+64 per q), col (tid&7)*8.
    // LDS dest = wave-uniform base + lane*16B (verified linear mapping).
    const int srow = tid >> 3;          // 0..63
    const int scol = (tid & 7) * 8;     // 0..56
    const u16* gA = A + (size_t)(bm*256 + srow)*1024 + scol;
    const u16* gB = B + (size_t)(bn*256 + srow)*1024 + scol;

    auto stageA = [&](int buf, int h, int t1) {
        size_t ko = (size_t)t1 * 64;
        #pragma unroll
        for (int q = 0; q < 2; q++)
            gload16(gA + (size_t)(h*128 + q*64)*1024 + ko,
                    &As[buf][(h*128 + q*64 + w*8)*64]);
    };
    auto stageB = [&](int buf, int h, int t1) {
        size_t ko = (size_t)t1 * 64;
        #pragma unroll
        for (int q = 0; q < 2; q++)
            gload16(gB + (size_t)(h*128 + q*64)*1024 + ko,
                    &Bs[buf][(h*128 + q*64 + w*8)*64]);
    };

    f32x4 acc[8][4];
    #pragma unroll
    for (int i = 0; i < 8; i++)
        #pragma unroll
        for (int j = 0; j < 4; j++)
            acc[i][j] = (f32x4){0.f, 0.f, 0.f, 0.f};

    constexpr int NT = 16;              // K/64
    // prologue: tile 0 -> buf0 (A0,B0,A1,B1)
    stageA(0, 0, 0); stageB(0, 0, 0); stageA(0, 1, 0); stageB(0, 1, 0);

    for (int t = 0; t < NT; ++t) {
        const int cur = t & 1;
        const bool more = (t + 1 < NT);
        #pragma unroll
        for (int p = 0; p < 4; ++p) {
            if (more) {                       // issue tile t+1 half-tile p
                if (p == 0)      stageA(cur ^ 1, 0, t + 1);
                else if (p == 1) stageB(cur ^ 1, 0, t + 1);
                else if (p == 2) stageA(cur ^ 1, 1, t + 1);
                else             stageB(cur ^ 1, 1, t + 1);
            }
            if (p == 0) { if (more) wait_vm<6>(); else wait_vm<4>(); }
            if (p == 1) { if (more) wait_vm<4>(); else wait_vm<0>(); }
            barrier_raw();                    // global visibility of retired DMA
            const int rh = p >> 1, ch = p & 1;
            frag8 af[4][2], bfr[2][2];
            #pragma unroll
            for (int i = 0; i < 4; i++)
                #pragma unroll
                for (int kk = 0; kk < 2; kk++)
                    af[i][kk] = *(frag8*)&As[cur][(wm + rh*64 + i*16 + lm)*64
                                                  + kk*32 + quad*8];
            #pragma unroll
            for (int j = 0; j < 2; j++)
                #pragma unroll
                for (int kk = 0; kk < 2; kk++)
                    bfr[j][kk] = *(frag8*)&Bs[cur][(wn + ch*32 + j*16 + lm)*64
                                                   + kk*32 + quad*8];
            __builtin_amdgcn_s_setprio(1);
            #pragma unroll
            for (int kk = 0; kk < 2; kk++)
                #pragma unroll
                for (int i = 0; i < 4; i++)
                    #pragma unroll
                    for (int j = 0; j < 2; j++)
                        acc[rh*4 + i][ch*2 + j] =
                            __builtin_amdgcn_mfma_f32_16x16x32_bf16(
                                af[i][kk], bfr[j][kk], acc[rh*4 + i][ch*2 + j],
                                0, 0, 0);
            __builtin_amdgcn_s_setprio(0);
        }
    }

    // epilogue: relu^2 -> bf16. row = wm + (I>>2)*64 + (I&3)*16 + quad*4 + r
    #pragma unroll
    for (int I = 0; I < 8; I++) {
        #pragma unroll
        for (int J = 0; J < 4; J++) {
            const int gcol = bn*256 + wn + (J >> 1)*32 + (J & 1)*16 + lm;
            #pragma unroll
            for (int r = 0; r < 4; r++) {
                const int grow = bm*256 + wm + (I >> 2)*64 + (I & 3)*16
                               + quad*4 + r;
                float vv = fmaxf(acc[I][J][r], 0.f);
                C[(size_t)grow * FFD + gcol] = f2bf(vv * vv);
            }
        }
    }
}

// ---------------------------------------------------------------------------
// Fused QKV + meta1 GEMM (unchanged, R3-proven)
// ---------------------------------------------------------------------------
__global__ __launch_bounds__(256)
void gemm_qkvm(const u16* __restrict__ xb,
               const u16* __restrict__ Wqb, const u16* __restrict__ Wkb,
               const u16* __restrict__ Wvb, const u16* __restrict__ Wm1b,
               const void* __restrict__ bm1,
               u16* __restrict__ q, u16* __restrict__ k, u16* __restrict__ v,
               float* __restrict__ hid, const u32* __restrict__ flags)
{
    __shared__ u16 As[2][128 * 32];
    __shared__ u16 Bs[2][128 * 32];
    const int tid = threadIdx.x;
    int bm, bn;
    xcd_map(blockIdx.x, 832, 26, bm, bn);

    const int bsel = bn >> 3;                    // 0 q, 1 k, 2 v, 3 meta
    const u16* B = (bsel == 0) ? Wqb : (bsel == 1) ? Wkb
                 : (bsel == 2) ? Wvb : Wm1b;

    const int wave = tid >> 6, lane = tid & 63;
    const int lm = lane & 15, quad = lane >> 4;
    const int wm = (wave >> 1) * 64, wn = (wave & 1) * 64;

    const int srow = lane >> 2;
    const int scol = (lane & 3) * 8;
    const u16* gA = xb + (size_t)(bm*128 + wave*32 + srow)*CC + scol;
    const u16* gB = B + (size_t)((bn & 7)*128 + wave*32 + srow)*CC + scol;
    const size_t s16 = (size_t)16 * CC;

    f32x4 acc[4][4];
    #pragma unroll
    for (int i = 0; i < 4; i++)
        #pragma unroll
        for (int j = 0; j < 4; j++)
            acc[i][j] = (f32x4){0.f, 0.f, 0.f, 0.f};

    auto stage = [&](int buf, int kk) {
        gload16(gA + kk,       &As[buf][wave*1024]);
        gload16(gA + kk + s16, &As[buf][wave*1024 + 512]);
        gload16(gB + kk,       &Bs[buf][wave*1024]);
        gload16(gB + kk + s16, &Bs[buf][wave*1024 + 512]);
    };

    stage(0, 0);
    __syncthreads();
    int cur = 0;
    for (int k0 = 0; k0 < CC; k0 += 32) {
        if (k0 + 32 < CC) stage(cur ^ 1, k0 + 32);
        frag8 af[4], bfr[4];
        #pragma unroll
        for (int i = 0; i < 4; i++) {
            af[i]  = *(frag8*)&As[cur][(wm + i*16 + lm)*32 + quad*8];
            bfr[i] = *(frag8*)&Bs[cur][(wn + i*16 + lm)*32 + quad*8];
        }
        #pragma unroll
        for (int i = 0; i < 4; i++)
            #pragma unroll
            for (int j = 0; j < 4; j++)
                acc[i][j] = __builtin_amdgcn_mfma_f32_16x16x32_bf16(
                    af[i], bfr[j], acc[i][j], 0, 0, 0);
        __syncthreads();
        cur ^= 1;
    }

    if (bsel < 3) {
        u16* outp = (bsel == 0) ? q : (bsel == 1) ? k : v;
        #pragma unroll
        for (int i = 0; i < 4; i++) {
            #pragma unroll
            for (int j = 0; j < 4; j++) {
                const int gcol = (bn & 7)*128 + wn + j*16 + lm;
                #pragma unroll
                for (int r = 0; r < 4; r++) {
                    const int grow = bm*128 + wm + i*16 + quad*4 + r;
                    outp[(size_t)grow * CC + gcol] = f2bf(acc[i][j][r]);
                }
            }
        }
    } else {
        const bool biasf = is_f32(flags, 5);
        #pragma unroll
        for (int i = 0; i < 4; i++) {
            #pragma unroll
            for (int j = 0; j < 4; j++) {
                const int gcol = (bn & 7)*128 + wn + j*16 + lm;   // 0..255
                float bia = biasf ? ((const float*)bm1)[gcol]
                                  : bf2f(((const u16*)bm1)[gcol]);
                #pragma unroll
                for (int r = 0; r < 4; r++) {
                    const int grow = bm*128 + wm + i*16 + quad*4 + r;
                    hid[(size_t)grow * HID + gcol] = fmaxf(acc[i][j][r] + bia, 0.f);
                }
            }
        }
    }
}

// ---------------------------------------------------------------------------
// meta2 (unchanged)
// ---------------------------------------------------------------------------
__global__ __launch_bounds__(256)
void meta2_kernel(const float* __restrict__ hid, const void* __restrict__ Wm2,
                  const void* __restrict__ bm2, float* __restrict__ g,
                  float* __restrict__ dec, const u32* __restrict__ flags)
{
    const bool wf = is_f32(flags, 6);
    const bool bf = is_f32(flags, 7);
    __shared__ float hs[16][257];
    __shared__ float wsm[16][257];
    int tid  = threadIdx.x;
    int tok0 = blockIdx.x * 16;
    for (int i = tid; i < 16*256; i += 256) {
        wsm[i >> 8][i & 255] = wf ? ((const float*)Wm2)[i] : bf2f(((const u16*)Wm2)[i]);
        hs [i >> 8][i & 255] = hid[(size_t)tok0*256 + i];
    }
    __syncthreads();
    int tok = tid >> 4, hh = tid & 15;
    float s = 0.f;
    #pragma unroll 8
    for (int kk = 0; kk < 256; kk++) s = fmaf(hs[tok][kk], wsm[hh][kk], s);
    s += bf ? ((const float*)bm2)[hh] : bf2f(((const u16*)bm2)[hh]);
    float sg = 1.f / (1.f + expf(-s));
    int idx = (tok0 + tok) * HH + hh;
    g[idx]   = sg;
    dec[idx] = 1.f - sg;
}

// wave-parallel inclusive prefix sum of log(dec) over 64 chunk-steps
__device__ __forceinline__ void cum_prefix(const float* dd, float* cum, int tid)
{
    if (tid < 64) {
        float lw = logf(fmaxf(dd[tid], 1e-30f));
        #pragma unroll
        for (int off = 1; off < 64; off <<= 1) {
            float nv = __shfl_up(lw, off, 64);
            if (tid >= off) lw += nv;
        }
        cum[tid] = lw;
    }
    __syncthreads();
}

// ---------------------------------------------------------------------------
// scan pass 1 — MFMA version (R12-proven)
// ---------------------------------------------------------------------------
__global__ __launch_bounds__(256)
void scan_pass1(const u16* __restrict__ kbuf, const u16* __restrict__ vbuf,
                const float* __restrict__ g, const float* __restrict__ dec,
                float* __restrict__ Mb, float* __restrict__ Pb)
{
    __shared__ u16 kt[64*72];     // A: rows d, cols s (sw-scaled bf16)
    __shared__ u16 vt[64*72];     // B: rows e, cols s
    __shared__ float dd[64], gg[64], cum[64], sw[64];
    int tid = threadIdx.x;
    int bhc = blockIdx.x;
    int c = bhc & 31, h = (bhc >> 5) & 15, b = bhc >> 9;
    int t0 = c * CT;
    size_t rowbase = ((size_t)(b*TT + t0))*CC + h*DD;

    if (tid < 64) {
        int gidx = (b*TT + t0 + tid)*HH + h;
        dd[tid] = dec[gidx];
        gg[tid] = g[gidx];
    }
    __syncthreads();
    cum_prefix(dd, cum, tid);
    float ctot = cum[63];
    if (tid < 64) sw[tid] = gg[tid] * expf(ctot - cum[tid]);
    __syncthreads();

    #pragma unroll 4
    for (int i = tid; i < 4096; i += 256) {
        int ss = i >> 6, d = i & 63;
        size_t gi = rowbase + (size_t)ss*CC + d;
        kt[d*72 + ss] = f2bf(sw[ss] * bf2f(kbuf[gi]));
        vt[d*72 + ss] = vbuf[gi];          // d plays the e role here
    }
    __syncthreads();

    const int w = tid >> 6, lane = tid & 63;
    const int lm = lane & 15, quad = lane >> 4;

    f32x4 mf[4];
    #pragma unroll
    for (int j = 0; j < 4; j++) mf[j] = (f32x4){0.f,0.f,0.f,0.f};
    #pragma unroll
    for (int kk = 0; kk < 2; kk++) {
        frag8 aK = *(frag8*)&kt[(w*16 + lm)*72 + kk*32 + quad*8];
        #pragma unroll
        for (int j = 0; j < 4; j++) {
            frag8 bV = *(frag8*)&vt[(j*16 + lm)*72 + kk*32 + quad*8];
            mf[j] = __builtin_amdgcn_mfma_f32_16x16x32_bf16(aK, bV, mf[j], 0, 0, 0);
        }
    }

    size_t base = (size_t)bhc * 4096;
    #pragma unroll
    for (int r = 0; r < 4; r++) {
        int d = w*16 + quad*4 + r;
        #pragma unroll
        for (int j = 0; j < 4; j++)
            Mb[base + (size_t)d*64 + j*16 + lm] = mf[j][r];
    }
    if (tid == 0) Pb[bhc] = expf(ctot);
}

// ---------------------------------------------------------------------------
// scan pass 2 (unchanged)
// ---------------------------------------------------------------------------
__global__ __launch_bounds__(256)
void scan_pass2(float* __restrict__ MS, const float* __restrict__ Pb)
{
    int bh = blockIdx.x >> 4, grp = blockIdx.x & 15, tid = threadIdx.x;
    int eo = grp*256 + tid;
    float st = 0.f;
    for (int c = 0; c < NC; c++) {
        size_t e = ((size_t)bh*NC + c) * 4096 + eo;
        float p = Pb[bh*NC + c];
        float m = MS[e];
        MS[e] = st;
        st = fmaf(p, st, m);
    }
}

// ---------------------------------------------------------------------------
// fused scan pass 3 — MFMA version (R10-proven)
// ---------------------------------------------------------------------------
__global__ __launch_bounds__(256)
void scan_pass3(const u16* __restrict__ qbuf, const u16* __restrict__ kbuf,
                const u16* __restrict__ vbuf, const float* __restrict__ g,
                const float* __restrict__ dec, const float* __restrict__ Sb,
                u16* __restrict__ y)
{
    __shared__ u16 qs16[64*72];    // q rows t, cols d
    __shared__ u16 ks16[64*72];    // k rows s, cols d
    __shared__ u16 vt16[64*72];    // v^T rows e, cols s
    __shared__ u16 aws16[64*72];   // Aws rows t, cols s
    __shared__ float Ss_t[64*68];  // S^T rows e, cols d
    __shared__ float dd[64], gg[64], cum[64];
    int tid = threadIdx.x;
    int bhc = blockIdx.x;
    int c = bhc & 31, h = (bhc >> 5) & 15, b = bhc >> 9;
    int t0 = c * CT;
    size_t rowbase = ((size_t)(b*TT + t0))*CC + h*DD;
    size_t sbase = (size_t)bhc * 4096;

    {
        int sr = tid >> 2, d0 = (tid & 3) * 16;
        size_t gq = rowbase + (size_t)sr*CC + d0;
        *(uint4*)&qs16[sr*72 + d0]     = *(const uint4*)&qbuf[gq];
        *(uint4*)&qs16[sr*72 + d0 + 8] = *(const uint4*)&qbuf[gq + 8];
        *(uint4*)&ks16[sr*72 + d0]     = *(const uint4*)&kbuf[gq];
        *(uint4*)&ks16[sr*72 + d0 + 8] = *(const uint4*)&kbuf[gq + 8];
        #pragma unroll 4
        for (int i = tid; i < 4096; i += 256) {
            int ss = i >> 6, e = i & 63;
            vt16[e*72 + ss] = vbuf[rowbase + (size_t)ss*CC + e];
        }
        int dr = tid >> 2, e0 = (tid & 3) * 16;
        #pragma unroll
        for (int m = 0; m < 4; m++) {
            float4 sv4 = *(const float4*)&Sb[sbase + (size_t)dr*64 + e0 + m*4];
            Ss_t[(e0 + m*4 + 0)*68 + dr] = sv4.x;
            Ss_t[(e0 + m*4 + 1)*68 + dr] = sv4.y;
            Ss_t[(e0 + m*4 + 2)*68 + dr] = sv4.z;
            Ss_t[(e0 + m*4 + 3)*68 + dr] = sv4.w;
        }
        if (tid < 64) {
            int gidx = (b*TT + t0 + tid)*HH + h;
            dd[tid] = dec[gidx];
            gg[tid] = g[gidx];
        }
    }
    __syncthreads();
    cum_prefix(dd, cum, tid);

    const int w = tid >> 6, lane = tid & 63;
    const int lm = lane & 15, quad = lane >> 4;

    f32x4 a1f[4];
    #pragma unroll
    for (int j = 0; j < 4; j++) a1f[j] = (f32x4){0.f,0.f,0.f,0.f};
    #pragma unroll
    for (int kk = 0; kk < 2; kk++) {
        frag8 aq = *(frag8*)&qs16[(w*16 + lm)*72 + kk*32 + quad*8];
        #pragma unroll
        for (int j = 0; j < 4; j++) {
            frag8 bk = *(frag8*)&ks16[(j*16 + lm)*72 + kk*32 + quad*8];
            a1f[j] = __builtin_amdgcn_mfma_f32_16x16x32_bf16(aq, bk, a1f[j], 0, 0, 0);
        }
    }

    #pragma unroll
    for (int j = 0; j < 4; j++) {
        #pragma unroll
        for (int r = 0; r < 4; r++) {
            int t = w*16 + quad*4 + r, s = j*16 + lm;
            float wgt = (s <= t) ? gg[s] * expf(cum[t] - cum[s]) : 0.f;
            aws16[t*72 + s] = f2bf(wgt * a1f[j][r]);
        }
    }
    __syncthreads();

    f32x4 of[4];
    #pragma unroll
    for (int j = 0; j < 4; j++) of[j] = (f32x4){0.f,0.f,0.f,0.f};
    #pragma unroll
    for (int kk = 0; kk < 2; kk++) {
        frag8 aA = *(frag8*)&aws16[(w*16 + lm)*72 + kk*32 + quad*8];
        #pragma unroll
        for (int j = 0; j < 4; j++) {
            frag8 bV = *(frag8*)&vt16[(j*16 + lm)*72 + kk*32 + quad*8];
            of[j] = __builtin_amdgcn_mfma_f32_16x16x32_bf16(aA, bV, of[j], 0, 0, 0);
        }
    }

    float o2v[4][4] = {};          // [j][r]
    for (int d8 = 0; d8 < 8; d8++) {
        frag8 qr[4];
        #pragma unroll
        for (int r = 0; r < 4; r++)
            qr[r] = *(frag8*)&qs16[(w*16 + quad*4 + r)*72 + d8*8];
        float qv[4][8];
        #pragma unroll
        for (int r = 0; r < 4; r++)
            #pragma unroll
            for (int d2 = 0; d2 < 8; d2++)
                qv[r][d2] = bf2f((u16)qr[r][d2]);
        #pragma unroll
        for (int j = 0; j < 4; j++) {
            int e = j*16 + lm;
            float4 s0 = *(float4*)&Ss_t[e*68 + d8*8];
            float4 s1 = *(float4*)&Ss_t[e*68 + d8*8 + 4];
            float sv[8] = {s0.x, s0.y, s0.z, s0.w, s1.x, s1.y, s1.z, s1.w};
            #pragma unroll
            for (int d2 = 0; d2 < 8; d2++)
                #pragma unroll
                for (int r = 0; r < 4; r++)
                    o2v[j][r] = fmaf(qv[r][d2], sv[d2], o2v[j][r]);
        }
    }

    #pragma unroll
    for (int r = 0; r < 4; r++) {
        int t = w*16 + quad*4 + r;
        float cd = expf(cum[t]);
        size_t obase = rowbase + (size_t)t*CC;
        #pragma unroll
        for (int j = 0; j < 4; j++)
            y[obase + j*16 + lm] = f2bf(fmaf(cd, o2v[j][r], of[j][r]));
    }
}

// ---------------------------------------------------------------------------
// rmsnorm v3 (unchanged)
// ---------------------------------------------------------------------------
__global__ __launch_bounds__(256)
void rmsnorm_kernel(const float* __restrict__ p0, const float* __restrict__ p1,
                    void* __restrict__ yres, u16* __restrict__ yn,
                    const u32* __restrict__ flags)
{
    const bool of32 = flags[0] != 0;
    __shared__ float red[4];
    __shared__ float sscale;
    int row = blockIdx.x, tid = threadIdx.x;
    size_t base = (size_t)row*CC + tid*4;
    float4 a = *(const float4*)&p0[base];
    float4 b = *(const float4*)&p1[base];
    float v0 = a.x + b.x, v1 = a.y + b.y, v2 = a.z + b.z, v3 = a.w + b.w;
    if (of32) {
        *(float4*)((float*)yres + base) = make_float4(v0, v1, v2, v3);
    } else {
        u16* yr = (u16*)yres + base;
        yr[0] = f2bf(v0); yr[1] = f2bf(v1); yr[2] = f2bf(v2); yr[3] = f2bf(v3);
    }
    float p = v0*v0 + v1*v1 + v2*v2 + v3*v3;
    #pragma unroll
    for (int off = 32; off > 0; off >>= 1) p += __shfl_down(p, off, 64);
    if ((tid & 63) == 0) red[tid >> 6] = p;
    __syncthreads();
    if (tid == 0) {
        float tot = red[0] + red[1] + red[2] + red[3];
        sscale = rsqrtf(tot * (1.0f/1024.0f) + 1.1920928955078125e-07f);
    }
    __syncthreads();
    float sc = sscale;
    yn[base + 0] = f2bf(v0 * sc);
    yn[base + 1] = f2bf(v1 * sc);
    yn[base + 2] = f2bf(v2 * sc);
    yn[base + 3] = f2bf(v3 * sc);
}

// ---------------------------------------------------------------------------
// Workspace layout (peak 48 MB + 64 B, phase-aliased; residual lives in d_out)
// ---------------------------------------------------------------------------
extern "C" void kernel_launch(void* const* d_in, const int* in_sizes, int n_in,
                              void* d_out, int out_size, void* d_ws, size_t ws_size,
                              hipStream_t stream)
{
    char* ws = (char*)d_ws;
    u16*   xb     = (u16*)  (ws + 32*MB);
    u16*   Wqb    = (u16*)  (ws + 40*MB);
    u16*   Wkb    = (u16*)  (ws + 42*MB);
    u16*   Wvb    = (u16*)  (ws + 44*MB);
    u16*   Wm1b   = (u16*)  (ws + 46*MB);
    u16*   Wprojb = (u16*)  (ws + 8*MB);
    u16*   q      = (u16*)  (ws + 0*MB);
    u16*   k      = (u16*)  (ws + 16*MB);
    u16*   v      = (u16*)  (ws + 24*MB);
    float* hid    = (float*)(ws + 10*MB);
    float* g      = (float*)(ws + 14*MB);
    float* dec    = (float*)(ws + 14*MB + 262144);
    float* Pb     = (float*)(ws + 14*MB + 524288);
    float* MS     = (float*)(ws + 32*MB);
    u16*   yat    = q;                      // pass3 writes over q (exact alias)
    float* p0     = (float*)(ws + 16*MB);   // over k,v after scan3
    float* p1     = (float*)(ws + 32*MB);   // over MS after scan3
    u16*   yn     = (u16*)  (ws + 0*MB);    // over yat after proj
    u16*   Wfcb   = (u16*)  (ws + 8*MB);    // over Wprojb/hid/g after proj
    u16*   h1     = (u16*)  (ws + 16*MB);   // over p0,p1 after rmsnorm
    u16*   Wcpb   = (u16*)  (ws + 0*MB);    // over yn after fc
    u32*   flags  = (u32*)  (ws + 48*MB);

    InPtrs ip;
    for (int i = 0; i < 11; i++) { ip.p[i] = d_in[i]; ip.n[i] = in_sizes[i]; }
    sniff_kernel<<<1, 64, 0, stream>>>(ip, flags);

    // conv1: x, Wq, Wk, Wv, Wm1, Wproj -> bf16
    ConvArgs c1{};
    c1.src[0] = d_in[0]; c1.dst[0] = xb;     c1.flag[0] = 0;
    c1.src[1] = d_in[1]; c1.dst[1] = Wqb;    c1.flag[1] = 1;
    c1.src[2] = d_in[2]; c1.dst[2] = Wkb;    c1.flag[2] = 2;
    c1.src[3] = d_in[3]; c1.dst[3] = Wvb;    c1.flag[3] = 3;
    c1.src[4] = d_in[4]; c1.dst[4] = Wm1b;   c1.flag[4] = 4;
    c1.src[5] = d_in[8]; c1.dst[5] = Wprojb; c1.flag[5] = 8;
    {
        int nb[6] = {2048, 512, 512, 512, 128, 512};
        int cum = 0;
        for (int i = 0; i < 6; i++) { c1.bstart[i] = cum; cum += nb[i]; }
        c1.bstart[6] = cum;
        c1.nseg = 6;
        conv_kernel<<<cum, 256, 0, stream>>>(c1, flags);
    }

    // fused qkv + meta1 (832 blocks, XCD-swizzled)
    gemm_qkvm<<<832, 256, 0, stream>>>(xb, Wqb, Wkb, Wvb, Wm1b, d_in[5],
                                       q, k, v, hid, flags);
    meta2_kernel<<<NTOK/16, 256, 0, stream>>>(hid, d_in[6], d_in[7], g, dec, flags);
    // chunked gated linear-attention scan
    scan_pass1<<<NCHK, 256, 0, stream>>>(k, v, g, dec, MS, Pb);
    scan_pass2<<<NBH*16, 256, 0, stream>>>(MS, Pb);
    scan_pass3<<<NCHK, 256, 0, stream>>>(q, k, v, g, dec, MS, yat);
    // proj: split-K x2 -> f32 partials p0,p1 (proven 128x128 config)
    gemm_nt<0,128,128,1><<<dim3(256, 2), 256, 0, stream>>>(yat, Wprojb, p0, p1,
        nullptr, NTOK, CC, 512, CC, CC, flags, -2);
    // conv2: Wfc -> bf16 (region free after proj)
    ConvArgs c2{};
    c2.src[0] = d_in[9]; c2.dst[0] = Wfcb; c2.flag[0] = 9;
    c2.bstart[0] = 0; for (int i = 1; i < 7; i++) c2.bstart[i] = 2048;
    c2.nseg = 1;
    conv_kernel<<<2048, 256, 0, stream>>>(c2, flags);
    // rmsnorm: combine partials, residual -> d_out, normed -> yn
    rmsnorm_kernel<<<NTOK, 256, 0, stream>>>(p0, p1, d_out, yn, flags);
    // squared-relu MLP: 8-wave 256^2 phase-split schedule (counted vmcnt)
    gemm_fc8<<<256, 512, 0, stream>>>(yn, Wfcb, h1);
    // conv3: Wcp -> bf16 (over yn, free after fc)
    ConvArgs c3{};
    c3.src[0] = d_in[10]; c3.dst[0] = Wcpb; c3.flag[0] = 10;
    c3.bstart[0] = 0; for (int i = 1; i < 7; i++) c3.bstart[i] = 2048;
    c3.nseg = 1;
    conv_kernel<<<2048, 256, 0, stream>>>(c3, flags);
    // final: out = residual(d_out) + h1 @ Wcp^T
    // R6-proven best: 64x64 tile, BK=64, 1024 blocks = 4/CU
    gemm_nt<3,64,64,2><<<dim3(1024, 1), 256, 0, stream>>>(h1, Wcpb, d_out, nullptr,
        d_out, NTOK, CC, FFD, FFD, FFD, flags, 0);
}

// Round 14
// 368.603 us; speedup vs baseline: 1.0626x; 1.0626x over previous
//
#include <hip/hip_runtime.h>
#include <math.h>

// Problem constants
#define BB   2
#define TT   2048
#define CC   1024
#define HH   16
#define DD   64
#define HID  256
#define FFD  4096
#define NTOK (BB*TT)        // 4096
#define CT   64             // scan chunk length
#define NC   (TT/CT)        // 32 chunks per sequence
#define NBH  (BB*HH)        // 32 sequences
#define NCHK (NBH*NC)       // 1024 chunk-blocks
#define MB   (1048576ULL)

typedef unsigned short u16;
typedef unsigned int   u32;
typedef __attribute__((ext_vector_type(8))) short frag8;   // 8 bf16 = 4 VGPRs
typedef __attribute__((ext_vector_type(4))) float f32x4;

__device__ __forceinline__ float bf2f(u16 h){
    union { u32 u; float f; } c; c.u = ((u32)h) << 16; return c.f;
}
__device__ __forceinline__ u16 f2bf(float f){
    union { float f; u32 u; } c; c.f = f;
    u32 u = c.u;
    u += 0x7FFFu + ((u >> 16) & 1u);   // RNE
    return (u16)(u >> 16);
}
// idx >= 0: runtime flag (1 = f32). idx == -1: bf16. idx == -2: f32.
__device__ __forceinline__ bool is_f32(const u32* flags, int idx) {
    if (idx == -2) return true;
    if (idx < 0)  return false;
    return flags[idx] != 0;
}

// async 16B global -> LDS (DMA; LDS dest = wave-uniform base + lane*16)
__device__ __forceinline__ void gload16(const void* g, void* l) {
    __builtin_amdgcn_global_load_lds(
        (const __attribute__((address_space(1))) u32*)g,
        (__attribute__((address_space(3))) u32*)l, 16, 0, 0);
}

// counted vmem wait (keeps N loads in flight across barriers)
template<int N> __device__ __forceinline__ void wait_vm() {
    if constexpr (N == 0)      asm volatile("s_waitcnt vmcnt(0)" ::: "memory");
    else if constexpr (N == 4) asm volatile("s_waitcnt vmcnt(4)" ::: "memory");
    else                       asm volatile("s_waitcnt vmcnt(6)" ::: "memory");
}
__device__ __forceinline__ void barrier_raw() {
    asm volatile("s_barrier" ::: "memory");     // NO implicit waitcnt drain
}

// ---------------------------------------------------------------------------
// dtype sniffer (unchanged)
// ---------------------------------------------------------------------------
struct InPtrs { const void* p[11]; int n[11]; };

__global__ __launch_bounds__(64)
void sniff_kernel(InPtrs ip, u32* __restrict__ flags)
{
    int lane = threadIdx.x;
    u32 f0 = 0;
    for (int i = 0; i < 11; i++) {
        const u16* p = (const u16*)ip.p[i];
        int cap = ip.n[i] < 256 ? ip.n[i] : 256;
        bool ok = true;
        for (int j = lane; j < cap; j += 64) {
            u16 u = p[j];
            u32 e = (u >> 7) & 0xFFu;
            bool good = (u == 0u) || (u == 0x8000u) || (e >= 64u && e < 192u);
            ok = ok && good;
        }
        unsigned long long ball = __ballot(ok);
        u32 fl = (ball == ~0ull) ? 0u : 1u;
        if (ip.n[i] < 64) fl = f0;       // tiny tensors inherit x's dtype
        if (i == 0) f0 = fl;
        if (lane == 0) flags[i] = fl;
    }
}

// ---------------------------------------------------------------------------
// bf16 pre-conversion (unchanged)
// ---------------------------------------------------------------------------
struct ConvArgs {
    const void* src[6];
    u16* dst[6];
    int flag[6];
    int bstart[7];
    int nseg;
};

__global__ __launch_bounds__(256)
void conv_kernel(ConvArgs a, const u32* __restrict__ flags)
{
    int b = blockIdx.x;
    int s = 0;
    #pragma unroll
    for (int i = 1; i < 6; i++) if (i < a.nseg && b >= a.bstart[i]) s = i;
    size_t off = ((size_t)(b - a.bstart[s])) * 2048 + (size_t)threadIdx.x * 8;
    u16* d = a.dst[s] + off;
    if (flags[a.flag[s]] != 0) {
        const float* sp = (const float*)a.src[s] + off;
        float4 x0 = *(const float4*)sp;
        float4 x1 = *(const float4*)(sp + 4);
        u16 buf[8];
        buf[0]=f2bf(x0.x); buf[1]=f2bf(x0.y); buf[2]=f2bf(x0.z); buf[3]=f2bf(x0.w);
        buf[4]=f2bf(x1.x); buf[5]=f2bf(x1.y); buf[6]=f2bf(x1.z); buf[7]=f2bf(x1.w);
        *(uint4*)d = *(uint4*)buf;
    } else {
        *(uint4*)d = *(const uint4*)((const u16*)a.src[s] + off);
    }
}

// XCD-aware block remap (unchanged): pure permutation, NB % 8 == 0.
__device__ __forceinline__ void xcd_map(int i, int NB, int gx, int& bm, int& bn)
{
    int per = NB >> 3;
    int iq  = (i & 7) * per + (i >> 3);
    bm = iq / gx;
    bn = iq % gx;
}

// ---------------------------------------------------------------------------
// NT GEMM, MFMA core, bf16 inputs, global_load_lds staging with 2-buffer
// pipeline (R6-proven best). BK = KS*32 as KS separate [rows][32] sub-tiles.
// MODE: 0 plain f32 partial (z ? Cm2 : Cm), 2 relu^2 -> bf16,
// 3 +residual(aux) -> Cm (dtype by oi).
// ---------------------------------------------------------------------------
template<int MODE, int BM, int BN, int KS>
__global__ __launch_bounds__(256)
void gemm_nt(const u16* __restrict__ A, const u16* __restrict__ B,
             void* Cm, void* Cm2, const void* aux,
             int M, int N, int K, int lda, int ldb,
             const u32* __restrict__ flags, int oi)
{
    constexpr int MFR = BM / 32;
    constexpr int NFR = BN / 32;
    constexpr int BKE = KS * 32;
    const bool of32 = is_f32(flags, oi);
    __shared__ u16 As[2][KS][BM * 32];
    __shared__ u16 Bs[2][KS][BN * 32];
    const int tid = threadIdx.x;
    int bm, bn;
    xcd_map(blockIdx.x, gridDim.x, N / BN, bm, bn);
    const int z = blockIdx.y;
    const size_t koff = (size_t)z * K;

    const int wave = tid >> 6, lane = tid & 63;
    const int lm = lane & 15, quad = lane >> 4;
    const int wm = (wave >> 1) * (BM / 2), wn = (wave & 1) * (BN / 2);

    const int srow = lane >> 2;           // 0..15
    const int scol = (lane & 3) * 8;      // 0,8,16,24
    const int arow = (BM == 128) ? (wave*32 + srow) : (wave*16 + srow);
    const int brow = (BN == 128) ? (wave*32 + srow) : (wave*16 + srow);
    const u16* gA = A + (size_t)(bm*BM + arow)*lda + koff + scol;
    const u16* gB = B + (size_t)(bn*BN + brow)*ldb + koff + scol;
    const size_t a16 = (size_t)16 * lda, b16 = (size_t)16 * ldb;

    f32x4 acc[MFR][NFR];
    #pragma unroll
    for (int i = 0; i < MFR; i++)
        #pragma unroll
        for (int j = 0; j < NFR; j++)
            acc[i][j] = (f32x4){0.f, 0.f, 0.f, 0.f};

    auto stage = [&](int buf, int kk) {
        #pragma unroll
        for (int ks = 0; ks < KS; ks++) {
            if constexpr (BM == 128) {
                gload16(gA + kk + ks*32,       &As[buf][ks][wave*1024]);
                gload16(gA + kk + ks*32 + a16, &As[buf][ks][wave*1024 + 512]);
            } else {
                gload16(gA + kk + ks*32, &As[buf][ks][wave*512]);
            }
            if constexpr (BN == 128) {
                gload16(gB + kk + ks*32,       &Bs[buf][ks][wave*1024]);
                gload16(gB + kk + ks*32 + b16, &Bs[buf][ks][wave*1024 + 512]);
            } else {
                gload16(gB + kk + ks*32, &Bs[buf][ks][wave*512]);
            }
        }
    };

    stage(0, 0);
    __syncthreads();                       // buf0 DMA landed
    int cur = 0;
    for (int k0 = 0; k0 < K; k0 += BKE) {
        if (k0 + BKE < K) stage(cur ^ 1, k0 + BKE);  // prefetch next tile
        #pragma unroll
        for (int ks = 0; ks < KS; ks++) {
            frag8 af[MFR], bfr[NFR];
            #pragma unroll
            for (int i = 0; i < MFR; i++)
                af[i]  = *(frag8*)&As[cur][ks][(wm + i*16 + lm)*32 + quad*8];
            #pragma unroll
            for (int j = 0; j < NFR; j++)
                bfr[j] = *(frag8*)&Bs[cur][ks][(wn + j*16 + lm)*32 + quad*8];
            #pragma unroll
            for (int i = 0; i < MFR; i++)
                #pragma unroll
                for (int j = 0; j < NFR; j++)
                    acc[i][j] = __builtin_amdgcn_mfma_f32_16x16x32_bf16(
                        af[i], bfr[j], acc[i][j], 0, 0, 0);
        }
        __syncthreads();                   // next-tile DMA landed; reads done
        cur ^= 1;
    }

    float* outF = (float*)(z ? Cm2 : Cm);
    // C/D map (m89/m91): col = lane&15, row = quad*4 + reg
    #pragma unroll
    for (int i = 0; i < MFR; i++) {
        #pragma unroll
        for (int j = 0; j < NFR; j++) {
            const int gcol = bn*BN + wn + j*16 + lm;
            #pragma unroll
            for (int r = 0; r < 4; r++) {
                const int grow = bm*BM + wm + i*16 + quad*4 + r;
                size_t off = (size_t)grow * N + gcol;
                float vv = acc[i][j][r];
                if constexpr (MODE == 0) {
                    outF[off] = vv;
                } else if constexpr (MODE == 2) {
                    vv = fmaxf(vv, 0.f);
                    ((u16*)Cm)[off] = f2bf(vv * vv);
                } else { // MODE 3: residual add, dtype-matched output
                    float res = of32 ? ((const float*)aux)[off]
                                     : bf2f(((const u16*)aux)[off]);
                    vv += res;
                    if (of32) ((float*)Cm)[off] = vv;
                    else      ((u16*)Cm)[off]   = f2bf(vv);
                }
            }
        }
    }
}

// ---------------------------------------------------------------------------
// fc GEMM, 8-wave 256x256 phase-split schedule with counted vmcnt (T3+T4)
// + T2 XOR swizzle (rule #21: linear DMA dest + pre-swizzled global SOURCE +
// swizzled READ; chunk ^= row&7 at 16B granularity — involution).
// h1 = relu(yn @ Wfc^T)^2. M=N=4096, K=1024.
// ---------------------------------------------------------------------------
__global__ __launch_bounds__(512)
void gemm_fc8(const u16* __restrict__ A, const u16* __restrict__ B,
              u16* __restrict__ C)
{
    __shared__ u16 As[2][256 * 64];
    __shared__ u16 Bs[2][256 * 64];
    const int tid = threadIdx.x;
    int bm, bn;
    xcd_map(blockIdx.x, 256, 16, bm, bn);

    const int w = tid >> 6, lane = tid & 63;
    const int lm = lane & 15, quad = lane >> 4;
    const int wm = (w >> 2) * 128, wn = (w & 3) * 64;

    // staging: lane covers LDS row ..+(tid>>3), chunk tid&7 (linear dest).
    // Pre-swizzled SOURCE column: chunk ^ (row&7), row&7 = (tid>>3)&7.
    const int srow = tid >> 3;          // 0..63
    const int scol = (((tid & 7) ^ ((tid >> 3) & 7))) * 8;   // T2 pre-swizzle
    const u16* gA = A + (size_t)(bm*256 + srow)*1024 + scol;
    const u16* gB = B + (size_t)(bn*256 + srow)*1024 + scol;

    auto stageA = [&](int buf, int h, int t1) {
        size_t ko = (size_t)t1 * 64;
        #pragma unroll
        for (int q = 0; q < 2; q++)
            gload16(gA + (size_t)(h*128 + q*64)*1024 + ko,
                    &As[buf][(h*128 + q*64 + w*8)*64]);
    };
    auto stageB = [&](int buf, int h, int t1) {
        size_t ko = (size_t)t1 * 64;
        #pragma unroll
        for (int q = 0; q < 2; q++)
            gload16(gB + (size_t)(h*128 + q*64)*1024 + ko,
                    &Bs[buf][(h*128 + q*64 + w*8)*64]);
    };

    f32x4 acc[8][4];
    #pragma unroll
    for (int i = 0; i < 8; i++)
        #pragma unroll
        for (int j = 0; j < 4; j++)
            acc[i][j] = (f32x4){0.f, 0.f, 0.f, 0.f};

    constexpr int NT = 16;              // K/64
    // prologue: tile 0 -> buf0 (A0,B0,A1,B1)
    stageA(0, 0, 0); stageB(0, 0, 0); stageA(0, 1, 0); stageB(0, 1, 0);

    const int rsw = (lm & 7);           // read-side swizzle key (row&7 == lm&7)
    for (int t = 0; t < NT; ++t) {
        const int cur = t & 1;
        const bool more = (t + 1 < NT);
        #pragma unroll
        for (int p = 0; p < 4; ++p) {
            if (more) {                       // issue tile t+1 half-tile p
                if (p == 0)      stageA(cur ^ 1, 0, t + 1);
                else if (p == 1) stageB(cur ^ 1, 0, t + 1);
                else if (p == 2) stageA(cur ^ 1, 1, t + 1);
                else             stageB(cur ^ 1, 1, t + 1);
            }
            if (p == 0) { if (more) wait_vm<6>(); else wait_vm<4>(); }
            if (p == 1) { if (more) wait_vm<4>(); else wait_vm<0>(); }
            barrier_raw();                    // global visibility of retired DMA
            const int rh = p >> 1, ch = p & 1;
            frag8 af[4][2], bfr[2][2];
            #pragma unroll
            for (int i = 0; i < 4; i++)
                #pragma unroll
                for (int kk = 0; kk < 2; kk++)
                    af[i][kk] = *(frag8*)&As[cur][(wm + rh*64 + i*16 + lm)*64
                                      + (((kk*4 + quad) ^ rsw) * 8)];
            #pragma unroll
            for (int j = 0; j < 2; j++)
                #pragma unroll
                for (int kk = 0; kk < 2; kk++)
                    bfr[j][kk] = *(frag8*)&Bs[cur][(wn + ch*32 + j*16 + lm)*64
                                      + (((kk*4 + quad) ^ rsw) * 8)];
            __builtin_amdgcn_s_setprio(1);
            #pragma unroll
            for (int kk = 0; kk < 2; kk++)
                #pragma unroll
                for (int i = 0; i < 4; i++)
                    #pragma unroll
                    for (int j = 0; j < 2; j++)
                        acc[rh*4 + i][ch*2 + j] =
                            __builtin_amdgcn_mfma_f32_16x16x32_bf16(
                                af[i][kk], bfr[j][kk], acc[rh*4 + i][ch*2 + j],
                                0, 0, 0);
            __builtin_amdgcn_s_setprio(0);
        }
    }

    // epilogue: relu^2 -> bf16. row = wm + (I>>2)*64 + (I&3)*16 + quad*4 + r
    #pragma unroll
    for (int I = 0; I < 8; I++) {
        #pragma unroll
        for (int J = 0; J < 4; J++) {
            const int gcol = bn*256 + wn + (J >> 1)*32 + (J & 1)*16 + lm;
            #pragma unroll
            for (int r = 0; r < 4; r++) {
                const int grow = bm*256 + wm + (I >> 2)*64 + (I & 3)*16
                               + quad*4 + r;
                float vv = fmaxf(acc[I][J][r], 0.f);
                C[(size_t)grow * FFD + gcol] = f2bf(vv * vv);
            }
        }
    }
}

// ---------------------------------------------------------------------------
// Fused QKV + meta1 GEMM (unchanged, R3-proven)
// ---------------------------------------------------------------------------
__global__ __launch_bounds__(256)
void gemm_qkvm(const u16* __restrict__ xb,
               const u16* __restrict__ Wqb, const u16* __restrict__ Wkb,
               const u16* __restrict__ Wvb, const u16* __restrict__ Wm1b,
               const void* __restrict__ bm1,
               u16* __restrict__ q, u16* __restrict__ k, u16* __restrict__ v,
               float* __restrict__ hid, const u32* __restrict__ flags)
{
    __shared__ u16 As[2][128 * 32];
    __shared__ u16 Bs[2][128 * 32];
    const int tid = threadIdx.x;
    int bm, bn;
    xcd_map(blockIdx.x, 832, 26, bm, bn);

    const int bsel = bn >> 3;                    // 0 q, 1 k, 2 v, 3 meta
    const u16* B = (bsel == 0) ? Wqb : (bsel == 1) ? Wkb
                 : (bsel == 2) ? Wvb : Wm1b;

    const int wave = tid >> 6, lane = tid & 63;
    const int lm = lane & 15, quad = lane >> 4;
    const int wm = (wave >> 1) * 64, wn = (wave & 1) * 64;

    const int srow = lane >> 2;
    const int scol = (lane & 3) * 8;
    const u16* gA = xb + (size_t)(bm*128 + wave*32 + srow)*CC + scol;
    const u16* gB = B + (size_t)((bn & 7)*128 + wave*32 + srow)*CC + scol;
    const size_t s16 = (size_t)16 * CC;

    f32x4 acc[4][4];
    #pragma unroll
    for (int i = 0; i < 4; i++)
        #pragma unroll
        for (int j = 0; j < 4; j++)
            acc[i][j] = (f32x4){0.f, 0.f, 0.f, 0.f};

    auto stage = [&](int buf, int kk) {
        gload16(gA + kk,       &As[buf][wave*1024]);
        gload16(gA + kk + s16, &As[buf][wave*1024 + 512]);
        gload16(gB + kk,       &Bs[buf][wave*1024]);
        gload16(gB + kk + s16, &Bs[buf][wave*1024 + 512]);
    };

    stage(0, 0);
    __syncthreads();
    int cur = 0;
    for (int k0 = 0; k0 < CC; k0 += 32) {
        if (k0 + 32 < CC) stage(cur ^ 1, k0 + 32);
        frag8 af[4], bfr[4];
        #pragma unroll
        for (int i = 0; i < 4; i++) {
            af[i]  = *(frag8*)&As[cur][(wm + i*16 + lm)*32 + quad*8];
            bfr[i] = *(frag8*)&Bs[cur][(wn + i*16 + lm)*32 + quad*8];
        }
        #pragma unroll
        for (int i = 0; i < 4; i++)
            #pragma unroll
            for (int j = 0; j < 4; j++)
                acc[i][j] = __builtin_amdgcn_mfma_f32_16x16x32_bf16(
                    af[i], bfr[j], acc[i][j], 0, 0, 0);
        __syncthreads();
        cur ^= 1;
    }

    if (bsel < 3) {
        u16* outp = (bsel == 0) ? q : (bsel == 1) ? k : v;
        #pragma unroll
        for (int i = 0; i < 4; i++) {
            #pragma unroll
            for (int j = 0; j < 4; j++) {
                const int gcol = (bn & 7)*128 + wn + j*16 + lm;
                #pragma unroll
                for (int r = 0; r < 4; r++) {
                    const int grow = bm*128 + wm + i*16 + quad*4 + r;
                    outp[(size_t)grow * CC + gcol] = f2bf(acc[i][j][r]);
                }
            }
        }
    } else {
        const bool biasf = is_f32(flags, 5);
        #pragma unroll
        for (int i = 0; i < 4; i++) {
            #pragma unroll
            for (int j = 0; j < 4; j++) {
                const int gcol = (bn & 7)*128 + wn + j*16 + lm;   // 0..255
                float bia = biasf ? ((const float*)bm1)[gcol]
                                  : bf2f(((const u16*)bm1)[gcol]);
                #pragma unroll
                for (int r = 0; r < 4; r++) {
                    const int grow = bm*128 + wm + i*16 + quad*4 + r;
                    hid[(size_t)grow * HID + gcol] = fmaxf(acc[i][j][r] + bia, 0.f);
                }
            }
        }
    }
}

// ---------------------------------------------------------------------------
// meta2 (unchanged)
// ---------------------------------------------------------------------------
__global__ __launch_bounds__(256)
void meta2_kernel(const float* __restrict__ hid, const void* __restrict__ Wm2,
                  const void* __restrict__ bm2, float* __restrict__ g,
                  float* __restrict__ dec, const u32* __restrict__ flags)
{
    const bool wf = is_f32(flags, 6);
    const bool bf = is_f32(flags, 7);
    __shared__ float hs[16][257];
    __shared__ float wsm[16][257];
    int tid  = threadIdx.x;
    int tok0 = blockIdx.x * 16;
    for (int i = tid; i < 16*256; i += 256) {
        wsm[i >> 8][i & 255] = wf ? ((const float*)Wm2)[i] : bf2f(((const u16*)Wm2)[i]);
        hs [i >> 8][i & 255] = hid[(size_t)tok0*256 + i];
    }
    __syncthreads();
    int tok = tid >> 4, hh = tid & 15;
    float s = 0.f;
    #pragma unroll 8
    for (int kk = 0; kk < 256; kk++) s = fmaf(hs[tok][kk], wsm[hh][kk], s);
    s += bf ? ((const float*)bm2)[hh] : bf2f(((const u16*)bm2)[hh]);
    float sg = 1.f / (1.f + expf(-s));
    int idx = (tok0 + tok) * HH + hh;
    g[idx]   = sg;
    dec[idx] = 1.f - sg;
}

// wave-parallel inclusive prefix sum of log(dec) over 64 chunk-steps
__device__ __forceinline__ void cum_prefix(const float* dd, float* cum, int tid)
{
    if (tid < 64) {
        float lw = logf(fmaxf(dd[tid], 1e-30f));
        #pragma unroll
        for (int off = 1; off < 64; off <<= 1) {
            float nv = __shfl_up(lw, off, 64);
            if (tid >= off) lw += nv;
        }
        cum[tid] = lw;
    }
    __syncthreads();
}

// ---------------------------------------------------------------------------
// scan pass 1 — MFMA version (R12-proven)
// ---------------------------------------------------------------------------
__global__ __launch_bounds__(256)
void scan_pass1(const u16* __restrict__ kbuf, const u16* __restrict__ vbuf,
                const float* __restrict__ g, const float* __restrict__ dec,
                float* __restrict__ Mb, float* __restrict__ Pb)
{
    __shared__ u16 kt[64*72];     // A: rows d, cols s (sw-scaled bf16)
    __shared__ u16 vt[64*72];     // B: rows e, cols s
    __shared__ float dd[64], gg[64], cum[64], sw[64];
    int tid = threadIdx.x;
    int bhc = blockIdx.x;
    int c = bhc & 31, h = (bhc >> 5) & 15, b = bhc >> 9;
    int t0 = c * CT;
    size_t rowbase = ((size_t)(b*TT + t0))*CC + h*DD;

    if (tid < 64) {
        int gidx = (b*TT + t0 + tid)*HH + h;
        dd[tid] = dec[gidx];
        gg[tid] = g[gidx];
    }
    __syncthreads();
    cum_prefix(dd, cum, tid);
    float ctot = cum[63];
    if (tid < 64) sw[tid] = gg[tid] * expf(ctot - cum[tid]);
    __syncthreads();

    #pragma unroll 4
    for (int i = tid; i < 4096; i += 256) {
        int ss = i >> 6, d = i & 63;
        size_t gi = rowbase + (size_t)ss*CC + d;
        kt[d*72 + ss] = f2bf(sw[ss] * bf2f(kbuf[gi]));
        vt[d*72 + ss] = vbuf[gi];          // d plays the e role here
    }
    __syncthreads();

    const int w = tid >> 6, lane = tid & 63;
    const int lm = lane & 15, quad = lane >> 4;

    f32x4 mf[4];
    #pragma unroll
    for (int j = 0; j < 4; j++) mf[j] = (f32x4){0.f,0.f,0.f,0.f};
    #pragma unroll
    for (int kk = 0; kk < 2; kk++) {
        frag8 aK = *(frag8*)&kt[(w*16 + lm)*72 + kk*32 + quad*8];
        #pragma unroll
        for (int j = 0; j < 4; j++) {
            frag8 bV = *(frag8*)&vt[(j*16 + lm)*72 + kk*32 + quad*8];
            mf[j] = __builtin_amdgcn_mfma_f32_16x16x32_bf16(aK, bV, mf[j], 0, 0, 0);
        }
    }

    size_t base = (size_t)bhc * 4096;
    #pragma unroll
    for (int r = 0; r < 4; r++) {
        int d = w*16 + quad*4 + r;
        #pragma unroll
        for (int j = 0; j < 4; j++)
            Mb[base + (size_t)d*64 + j*16 + lm] = mf[j][r];
    }
    if (tid == 0) Pb[bhc] = expf(ctot);
}

// ---------------------------------------------------------------------------
// scan pass 2 (unchanged)
// ---------------------------------------------------------------------------
__global__ __launch_bounds__(256)
void scan_pass2(float* __restrict__ MS, const float* __restrict__ Pb)
{
    int bh = blockIdx.x >> 4, grp = blockIdx.x & 15, tid = threadIdx.x;
    int eo = grp*256 + tid;
    float st = 0.f;
    for (int c = 0; c < NC; c++) {
        size_t e = ((size_t)bh*NC + c) * 4096 + eo;
        float p = Pb[bh*NC + c];
        float m = MS[e];
        MS[e] = st;
        st = fmaf(p, st, m);
    }
}

// ---------------------------------------------------------------------------
// fused scan pass 3 — MFMA version (R10-proven)
// ---------------------------------------------------------------------------
__global__ __launch_bounds__(256)
void scan_pass3(const u16* __restrict__ qbuf, const u16* __restrict__ kbuf,
                const u16* __restrict__ vbuf, const float* __restrict__ g,
                const float* __restrict__ dec, const float* __restrict__ Sb,
                u16* __restrict__ y)
{
    __shared__ u16 qs16[64*72];    // q rows t, cols d
    __shared__ u16 ks16[64*72];    // k rows s, cols d
    __shared__ u16 vt16[64*72];    // v^T rows e, cols s
    __shared__ u16 aws16[64*72];   // Aws rows t, cols s
    __shared__ float Ss_t[64*68];  // S^T rows e, cols d
    __shared__ float dd[64], gg[64], cum[64];
    int tid = threadIdx.x;
    int bhc = blockIdx.x;
    int c = bhc & 31, h = (bhc >> 5) & 15, b = bhc >> 9;
    int t0 = c * CT;
    size_t rowbase = ((size_t)(b*TT + t0))*CC + h*DD;
    size_t sbase = (size_t)bhc * 4096;

    {
        int sr = tid >> 2, d0 = (tid & 3) * 16;
        size_t gq = rowbase + (size_t)sr*CC + d0;
        *(uint4*)&qs16[sr*72 + d0]     = *(const uint4*)&qbuf[gq];
        *(uint4*)&qs16[sr*72 + d0 + 8] = *(const uint4*)&qbuf[gq + 8];
        *(uint4*)&ks16[sr*72 + d0]     = *(const uint4*)&kbuf[gq];
        *(uint4*)&ks16[sr*72 + d0 + 8] = *(const uint4*)&kbuf[gq + 8];
        #pragma unroll 4
        for (int i = tid; i < 4096; i += 256) {
            int ss = i >> 6, e = i & 63;
            vt16[e*72 + ss] = vbuf[rowbase + (size_t)ss*CC + e];
        }
        int dr = tid >> 2, e0 = (tid & 3) * 16;
        #pragma unroll
        for (int m = 0; m < 4; m++) {
            float4 sv4 = *(const float4*)&Sb[sbase + (size_t)dr*64 + e0 + m*4];
            Ss_t[(e0 + m*4 + 0)*68 + dr] = sv4.x;
            Ss_t[(e0 + m*4 + 1)*68 + dr] = sv4.y;
            Ss_t[(e0 + m*4 + 2)*68 + dr] = sv4.z;
            Ss_t[(e0 + m*4 + 3)*68 + dr] = sv4.w;
        }
        if (tid < 64) {
            int gidx = (b*TT + t0 + tid)*HH + h;
            dd[tid] = dec[gidx];
            gg[tid] = g[gidx];
        }
    }
    __syncthreads();
    cum_prefix(dd, cum, tid);

    const int w = tid >> 6, lane = tid & 63;
    const int lm = lane & 15, quad = lane >> 4;

    f32x4 a1f[4];
    #pragma unroll
    for (int j = 0; j < 4; j++) a1f[j] = (f32x4){0.f,0.f,0.f,0.f};
    #pragma unroll
    for (int kk = 0; kk < 2; kk++) {
        frag8 aq = *(frag8*)&qs16[(w*16 + lm)*72 + kk*32 + quad*8];
        #pragma unroll
        for (int j = 0; j < 4; j++) {
            frag8 bk = *(frag8*)&ks16[(j*16 + lm)*72 + kk*32 + quad*8];
            a1f[j] = __builtin_amdgcn_mfma_f32_16x16x32_bf16(aq, bk, a1f[j], 0, 0, 0);
        }
    }

    #pragma unroll
    for (int j = 0; j < 4; j++) {
        #pragma unroll
        for (int r = 0; r < 4; r++) {
            int t = w*16 + quad*4 + r, s = j*16 + lm;
            float wgt = (s <= t) ? gg[s] * expf(cum[t] - cum[s]) : 0.f;
            aws16[t*72 + s] = f2bf(wgt * a1f[j][r]);
        }
    }
    __syncthreads();

    f32x4 of[4];
    #pragma unroll
    for (int j = 0; j < 4; j++) of[j] = (f32x4){0.f,0.f,0.f,0.f};
    #pragma unroll
    for (int kk = 0; kk < 2; kk++) {
        frag8 aA = *(frag8*)&aws16[(w*16 + lm)*72 + kk*32 + quad*8];
        #pragma unroll
        for (int j = 0; j < 4; j++) {
            frag8 bV = *(frag8*)&vt16[(j*16 + lm)*72 + kk*32 + quad*8];
            of[j] = __builtin_amdgcn_mfma_f32_16x16x32_bf16(aA, bV, of[j], 0, 0, 0);
        }
    }

    float o2v[4][4] = {};          // [j][r]
    for (int d8 = 0; d8 < 8; d8++) {
        frag8 qr[4];
        #pragma unroll
        for (int r = 0; r < 4; r++)
            qr[r] = *(frag8*)&qs16[(w*16 + quad*4 + r)*72 + d8*8];
        float qv[4][8];
        #pragma unroll
        for (int r = 0; r < 4; r++)
            #pragma unroll
            for (int d2 = 0; d2 < 8; d2++)
                qv[r][d2] = bf2f((u16)qr[r][d2]);
        #pragma unroll
        for (int j = 0; j < 4; j++) {
            int e = j*16 + lm;
            float4 s0 = *(float4*)&Ss_t[e*68 + d8*8];
            float4 s1 = *(float4*)&Ss_t[e*68 + d8*8 + 4];
            float sv[8] = {s0.x, s0.y, s0.z, s0.w, s1.x, s1.y, s1.z, s1.w};
            #pragma unroll
            for (int d2 = 0; d2 < 8; d2++)
                #pragma unroll
                for (int r = 0; r < 4; r++)
                    o2v[j][r] = fmaf(qv[r][d2], sv[d2], o2v[j][r]);
        }
    }

    #pragma unroll
    for (int r = 0; r < 4; r++) {
        int t = w*16 + quad*4 + r;
        float cd = expf(cum[t]);
        size_t obase = rowbase + (size_t)t*CC;
        #pragma unroll
        for (int j = 0; j < 4; j++)
            y[obase + j*16 + lm] = f2bf(fmaf(cd, o2v[j][r], of[j][r]));
    }
}

// ---------------------------------------------------------------------------
// rmsnorm v3 (unchanged)
// ---------------------------------------------------------------------------
__global__ __launch_bounds__(256)
void rmsnorm_kernel(const float* __restrict__ p0, const float* __restrict__ p1,
                    void* __restrict__ yres, u16* __restrict__ yn,
                    const u32* __restrict__ flags)
{
    const bool of32 = flags[0] != 0;
    __shared__ float red[4];
    __shared__ float sscale;
    int row = blockIdx.x, tid = threadIdx.x;
    size_t base = (size_t)row*CC + tid*4;
    float4 a = *(const float4*)&p0[base];
    float4 b = *(const float4*)&p1[base];
    float v0 = a.x + b.x, v1 = a.y + b.y, v2 = a.z + b.z, v3 = a.w + b.w;
    if (of32) {
        *(float4*)((float*)yres + base) = make_float4(v0, v1, v2, v3);
    } else {
        u16* yr = (u16*)yres + base;
        yr[0] = f2bf(v0); yr[1] = f2bf(v1); yr[2] = f2bf(v2); yr[3] = f2bf(v3);
    }
    float p = v0*v0 + v1*v1 + v2*v2 + v3*v3;
    #pragma unroll
    for (int off = 32; off > 0; off >>= 1) p += __shfl_down(p, off, 64);
    if ((tid & 63) == 0) red[tid >> 6] = p;
    __syncthreads();
    if (tid == 0) {
        float tot = red[0] + red[1] + red[2] + red[3];
        sscale = rsqrtf(tot * (1.0f/1024.0f) + 1.1920928955078125e-07f);
    }
    __syncthreads();
    float sc = sscale;
    yn[base + 0] = f2bf(v0 * sc);
    yn[base + 1] = f2bf(v1 * sc);
    yn[base + 2] = f2bf(v2 * sc);
    yn[base + 3] = f2bf(v3 * sc);
}

// ---------------------------------------------------------------------------
// Workspace layout (peak 48 MB + 64 B, phase-aliased; residual lives in d_out)
// ---------------------------------------------------------------------------
extern "C" void kernel_launch(void* const* d_in, const int* in_sizes, int n_in,
                              void* d_out, int out_size, void* d_ws, size_t ws_size,
                              hipStream_t stream)
{
    char* ws = (char*)d_ws;
    u16*   xb     = (u16*)  (ws + 32*MB);
    u16*   Wqb    = (u16*)  (ws + 40*MB);
    u16*   Wkb    = (u16*)  (ws + 42*MB);
    u16*   Wvb    = (u16*)  (ws + 44*MB);
    u16*   Wm1b   = (u16*)  (ws + 46*MB);
    u16*   Wprojb = (u16*)  (ws + 8*MB);
    u16*   q      = (u16*)  (ws + 0*MB);
    u16*   k      = (u16*)  (ws + 16*MB);
    u16*   v      = (u16*)  (ws + 24*MB);
    float* hid    = (float*)(ws + 10*MB);
    float* g      = (float*)(ws + 14*MB);
    float* dec    = (float*)(ws + 14*MB + 262144);
    float* Pb     = (float*)(ws + 14*MB + 524288);
    float* MS     = (float*)(ws + 32*MB);
    u16*   yat    = q;                      // pass3 writes over q (exact alias)
    float* p0     = (float*)(ws + 16*MB);   // over k,v after scan3
    float* p1     = (float*)(ws + 32*MB);   // over MS after scan3
    u16*   yn     = (u16*)  (ws + 0*MB);    // over yat after proj
    u16*   Wfcb   = (u16*)  (ws + 8*MB);    // over Wprojb/hid/g after proj
    u16*   h1     = (u16*)  (ws + 16*MB);   // over p0,p1 after rmsnorm
    u16*   Wcpb   = (u16*)  (ws + 0*MB);    // over yn after fc
    u32*   flags  = (u32*)  (ws + 48*MB);

    InPtrs ip;
    for (int i = 0; i < 11; i++) { ip.p[i] = d_in[i]; ip.n[i] = in_sizes[i]; }
    sniff_kernel<<<1, 64, 0, stream>>>(ip, flags);

    // conv1: x, Wq, Wk, Wv, Wm1, Wproj -> bf16
    ConvArgs c1{};
    c1.src[0] = d_in[0]; c1.dst[0] = xb;     c1.flag[0] = 0;
    c1.src[1] = d_in[1]; c1.dst[1] = Wqb;    c1.flag[1] = 1;
    c1.src[2] = d_in[2]; c1.dst[2] = Wkb;    c1.flag[2] = 2;
    c1.src[3] = d_in[3]; c1.dst[3] = Wvb;    c1.flag[3] = 3;
    c1.src[4] = d_in[4]; c1.dst[4] = Wm1b;   c1.flag[4] = 4;
    c1.src[5] = d_in[8]; c1.dst[5] = Wprojb; c1.flag[5] = 8;
    {
        int nb[6] = {2048, 512, 512, 512, 128, 512};
        int cum = 0;
        for (int i = 0; i < 6; i++) { c1.bstart[i] = cum; cum += nb[i]; }
        c1.bstart[6] = cum;
        c1.nseg = 6;
        conv_kernel<<<cum, 256, 0, stream>>>(c1, flags);
    }

    // fused qkv + meta1 (832 blocks, XCD-swizzled)
    gemm_qkvm<<<832, 256, 0, stream>>>(xb, Wqb, Wkb, Wvb, Wm1b, d_in[5],
                                       q, k, v, hid, flags);
    meta2_kernel<<<NTOK/16, 256, 0, stream>>>(hid, d_in[6], d_in[7], g, dec, flags);
    // chunked gated linear-attention scan
    scan_pass1<<<NCHK, 256, 0, stream>>>(k, v, g, dec, MS, Pb);
    scan_pass2<<<NBH*16, 256, 0, stream>>>(MS, Pb);
    scan_pass3<<<NCHK, 256, 0, stream>>>(q, k, v, g, dec, MS, yat);
    // proj: split-K x2 -> f32 partials p0,p1 (proven 128x128 config)
    gemm_nt<0,128,128,1><<<dim3(256, 2), 256, 0, stream>>>(yat, Wprojb, p0, p1,
        nullptr, NTOK, CC, 512, CC, CC, flags, -2);
    // conv2: Wfc -> bf16 (region free after proj)
    ConvArgs c2{};
    c2.src[0] = d_in[9]; c2.dst[0] = Wfcb; c2.flag[0] = 9;
    c2.bstart[0] = 0; for (int i = 1; i < 7; i++) c2.bstart[i] = 2048;
    c2.nseg = 1;
    conv_kernel<<<2048, 256, 0, stream>>>(c2, flags);
    // rmsnorm: combine partials, residual -> d_out, normed -> yn
    rmsnorm_kernel<<<NTOK, 256, 0, stream>>>(p0, p1, d_out, yn, flags);
    // squared-relu MLP: 8-wave 256^2 phase-split + T2 swizzle
    gemm_fc8<<<256, 512, 0, stream>>>(yn, Wfcb, h1);
    // conv3: Wcp -> bf16 (over yn, free after fc)
    ConvArgs c3{};
    c3.src[0] = d_in[10]; c3.dst[0] = Wcpb; c3.flag[0] = 10;
    c3.bstart[0] = 0; for (int i = 1; i < 7; i++) c3.bstart[i] = 2048;
    c3.nseg = 1;
    conv_kernel<<<2048, 256, 0, stream>>>(c3, flags);
    // final: out = residual(d_out) + h1 @ Wcp^T
    // R6-proven best: 64x64 tile, BK=64, 1024 blocks = 4/CU
    gemm_nt<3,64,64,2><<<dim3(1024, 1), 256, 0, stream>>>(h1, Wcpb, d_out, nullptr,
        d_out, NTOK, CC, FFD, FFD, FFD, flags, 0);
}

// Round 15
// 359.786 us; speedup vs baseline: 1.0886x; 1.0245x over previous
//
#include <hip/hip_runtime.h>
#include <math.h>

// Problem constants
#define BB   2
#define TT   2048
#define CC   1024
#define HH   16
#define DD   64
#define HID  256
#define FFD  4096
#define NTOK (BB*TT)        // 4096
#define CT   64             // scan chunk length
#define NC   (TT/CT)        // 32 chunks per sequence
#define NBH  (BB*HH)        // 32 sequences
#define NCHK (NBH*NC)       // 1024 chunk-blocks
#define MB   (1048576ULL)

typedef unsigned short u16;
typedef unsigned int   u32;
typedef __attribute__((ext_vector_type(8))) short frag8;   // 8 bf16 = 4 VGPRs
typedef __attribute__((ext_vector_type(4))) float f32x4;

__device__ __forceinline__ float bf2f(u16 h){
    union { u32 u; float f; } c; c.u = ((u32)h) << 16; return c.f;
}
__device__ __forceinline__ u16 f2bf(float f){
    union { float f; u32 u; } c; c.f = f;
    u32 u = c.u;
    u += 0x7FFFu + ((u >> 16) & 1u);   // RNE
    return (u16)(u >> 16);
}
// idx >= 0: runtime flag (1 = f32). idx == -1: bf16. idx == -2: f32.
__device__ __forceinline__ bool is_f32(const u32* flags, int idx) {
    if (idx == -2) return true;
    if (idx < 0)  return false;
    return flags[idx] != 0;
}

// async 16B global -> LDS (DMA; LDS dest = wave-uniform base + lane*16)
__device__ __forceinline__ void gload16(const void* g, void* l) {
    __builtin_amdgcn_global_load_lds(
        (const __attribute__((address_space(1))) u32*)g,
        (__attribute__((address_space(3))) u32*)l, 16, 0, 0);
}

// counted vmem wait (keeps N loads in flight across barriers)
template<int N> __device__ __forceinline__ void wait_vm() {
    if constexpr (N == 0)      asm volatile("s_waitcnt vmcnt(0)" ::: "memory");
    else if constexpr (N == 4) asm volatile("s_waitcnt vmcnt(4)" ::: "memory");
    else                       asm volatile("s_waitcnt vmcnt(6)" ::: "memory");
}
__device__ __forceinline__ void barrier_raw() {
    asm volatile("s_barrier" ::: "memory");     // NO implicit waitcnt drain
}

// ---------------------------------------------------------------------------
// dtype sniffer (unchanged)
// ---------------------------------------------------------------------------
struct InPtrs { const void* p[11]; int n[11]; };

__global__ __launch_bounds__(64)
void sniff_kernel(InPtrs ip, u32* __restrict__ flags)
{
    int lane = threadIdx.x;
    u32 f0 = 0;
    for (int i = 0; i < 11; i++) {
        const u16* p = (const u16*)ip.p[i];
        int cap = ip.n[i] < 256 ? ip.n[i] : 256;
        bool ok = true;
        for (int j = lane; j < cap; j += 64) {
            u16 u = p[j];
            u32 e = (u >> 7) & 0xFFu;
            bool good = (u == 0u) || (u == 0x8000u) || (e >= 64u && e < 192u);
            ok = ok && good;
        }
        unsigned long long ball = __ballot(ok);
        u32 fl = (ball == ~0ull) ? 0u : 1u;
        if (ip.n[i] < 64) fl = f0;       // tiny tensors inherit x's dtype
        if (i == 0) f0 = fl;
        if (lane == 0) flags[i] = fl;
    }
}

// ---------------------------------------------------------------------------
// bf16 pre-conversion (unchanged)
// ---------------------------------------------------------------------------
struct ConvArgs {
    const void* src[6];
    u16* dst[6];
    int flag[6];
    int bstart[7];
    int nseg;
};

__global__ __launch_bounds__(256)
void conv_kernel(ConvArgs a, const u32* __restrict__ flags)
{
    int b = blockIdx.x;
    int s = 0;
    #pragma unroll
    for (int i = 1; i < 6; i++) if (i < a.nseg && b >= a.bstart[i]) s = i;
    size_t off = ((size_t)(b - a.bstart[s])) * 2048 + (size_t)threadIdx.x * 8;
    u16* d = a.dst[s] + off;
    if (flags[a.flag[s]] != 0) {
        const float* sp = (const float*)a.src[s] + off;
        float4 x0 = *(const float4*)sp;
        float4 x1 = *(const float4*)(sp + 4);
        u16 buf[8];
        buf[0]=f2bf(x0.x); buf[1]=f2bf(x0.y); buf[2]=f2bf(x0.z); buf[3]=f2bf(x0.w);
        buf[4]=f2bf(x1.x); buf[5]=f2bf(x1.y); buf[6]=f2bf(x1.z); buf[7]=f2bf(x1.w);
        *(uint4*)d = *(uint4*)buf;
    } else {
        *(uint4*)d = *(const uint4*)((const u16*)a.src[s] + off);
    }
}

// XCD-aware block remap (unchanged): pure permutation, NB % 8 == 0.
__device__ __forceinline__ void xcd_map(int i, int NB, int gx, int& bm, int& bn)
{
    int per = NB >> 3;
    int iq  = (i & 7) * per + (i >> 3);
    bm = iq / gx;
    bn = iq % gx;
}

// ---------------------------------------------------------------------------
// NT GEMM, MFMA core, bf16 inputs, global_load_lds staging with 2-buffer
// pipeline (R6-proven best). BK = KS*32 as KS separate [rows][32] sub-tiles.
// MODE: 0 plain f32 partial (z ? Cm2 : Cm), 2 relu^2 -> bf16,
// 3 +residual(aux) -> Cm (dtype by oi).
// ---------------------------------------------------------------------------
template<int MODE, int BM, int BN, int KS>
__global__ __launch_bounds__(256)
void gemm_nt(const u16* __restrict__ A, const u16* __restrict__ B,
             void* Cm, void* Cm2, const void* aux,
             int M, int N, int K, int lda, int ldb,
             const u32* __restrict__ flags, int oi)
{
    constexpr int MFR = BM / 32;
    constexpr int NFR = BN / 32;
    constexpr int BKE = KS * 32;
    const bool of32 = is_f32(flags, oi);
    __shared__ u16 As[2][KS][BM * 32];
    __shared__ u16 Bs[2][KS][BN * 32];
    const int tid = threadIdx.x;
    int bm, bn;
    xcd_map(blockIdx.x, gridDim.x, N / BN, bm, bn);
    const int z = blockIdx.y;
    const size_t koff = (size_t)z * K;

    const int wave = tid >> 6, lane = tid & 63;
    const int lm = lane & 15, quad = lane >> 4;
    const int wm = (wave >> 1) * (BM / 2), wn = (wave & 1) * (BN / 2);

    const int srow = lane >> 2;           // 0..15
    const int scol = (lane & 3) * 8;      // 0,8,16,24
    const int arow = (BM == 128) ? (wave*32 + srow) : (wave*16 + srow);
    const int brow = (BN == 128) ? (wave*32 + srow) : (wave*16 + srow);
    const u16* gA = A + (size_t)(bm*BM + arow)*lda + koff + scol;
    const u16* gB = B + (size_t)(bn*BN + brow)*ldb + koff + scol;
    const size_t a16 = (size_t)16 * lda, b16 = (size_t)16 * ldb;

    f32x4 acc[MFR][NFR];
    #pragma unroll
    for (int i = 0; i < MFR; i++)
        #pragma unroll
        for (int j = 0; j < NFR; j++)
            acc[i][j] = (f32x4){0.f, 0.f, 0.f, 0.f};

    auto stage = [&](int buf, int kk) {
        #pragma unroll
        for (int ks = 0; ks < KS; ks++) {
            if constexpr (BM == 128) {
                gload16(gA + kk + ks*32,       &As[buf][ks][wave*1024]);
                gload16(gA + kk + ks*32 + a16, &As[buf][ks][wave*1024 + 512]);
            } else {
                gload16(gA + kk + ks*32, &As[buf][ks][wave*512]);
            }
            if constexpr (BN == 128) {
                gload16(gB + kk + ks*32,       &Bs[buf][ks][wave*1024]);
                gload16(gB + kk + ks*32 + b16, &Bs[buf][ks][wave*1024 + 512]);
            } else {
                gload16(gB + kk + ks*32, &Bs[buf][ks][wave*512]);
            }
        }
    };

    stage(0, 0);
    __syncthreads();                       // buf0 DMA landed
    int cur = 0;
    for (int k0 = 0; k0 < K; k0 += BKE) {
        if (k0 + BKE < K) stage(cur ^ 1, k0 + BKE);  // prefetch next tile
        #pragma unroll
        for (int ks = 0; ks < KS; ks++) {
            frag8 af[MFR], bfr[NFR];
            #pragma unroll
            for (int i = 0; i < MFR; i++)
                af[i]  = *(frag8*)&As[cur][ks][(wm + i*16 + lm)*32 + quad*8];
            #pragma unroll
            for (int j = 0; j < NFR; j++)
                bfr[j] = *(frag8*)&Bs[cur][ks][(wn + j*16 + lm)*32 + quad*8];
            #pragma unroll
            for (int i = 0; i < MFR; i++)
                #pragma unroll
                for (int j = 0; j < NFR; j++)
                    acc[i][j] = __builtin_amdgcn_mfma_f32_16x16x32_bf16(
                        af[i], bfr[j], acc[i][j], 0, 0, 0);
        }
        __syncthreads();                   // next-tile DMA landed; reads done
        cur ^= 1;
    }

    float* outF = (float*)(z ? Cm2 : Cm);
    // C/D map (m89/m91): col = lane&15, row = quad*4 + reg
    #pragma unroll
    for (int i = 0; i < MFR; i++) {
        #pragma unroll
        for (int j = 0; j < NFR; j++) {
            const int gcol = bn*BN + wn + j*16 + lm;
            #pragma unroll
            for (int r = 0; r < 4; r++) {
                const int grow = bm*BM + wm + i*16 + quad*4 + r;
                size_t off = (size_t)grow * N + gcol;
                float vv = acc[i][j][r];
                if constexpr (MODE == 0) {
                    outF[off] = vv;
                } else if constexpr (MODE == 2) {
                    vv = fmaxf(vv, 0.f);
                    ((u16*)Cm)[off] = f2bf(vv * vv);
                } else { // MODE 3: residual add, dtype-matched output
                    float res = of32 ? ((const float*)aux)[off]
                                     : bf2f(((const u16*)aux)[off]);
                    vv += res;
                    if (of32) ((float*)Cm)[off] = vv;
                    else      ((u16*)Cm)[off]   = f2bf(vv);
                }
            }
        }
    }
}

// ---------------------------------------------------------------------------
// fc GEMM, 8-wave 256x256 phase-split schedule with counted vmcnt (T3+T4)
// + T2 XOR swizzle (R14-proven): h1 = relu(yn @ Wfc^T)^2. M=N=4096, K=1024.
// ---------------------------------------------------------------------------
__global__ __launch_bounds__(512)
void gemm_fc8(const u16* __restrict__ A, const u16* __restrict__ B,
              u16* __restrict__ C)
{
    __shared__ u16 As[2][256 * 64];
    __shared__ u16 Bs[2][256 * 64];
    const int tid = threadIdx.x;
    int bm, bn;
    xcd_map(blockIdx.x, 256, 16, bm, bn);

    const int w = tid >> 6, lane = tid & 63;
    const int lm = lane & 15, quad = lane >> 4;
    const int wm = (w >> 2) * 128, wn = (w & 3) * 64;

    const int srow = tid >> 3;          // 0..63
    const int scol = (((tid & 7) ^ ((tid >> 3) & 7))) * 8;   // T2 pre-swizzle
    const u16* gA = A + (size_t)(bm*256 + srow)*1024 + scol;
    const u16* gB = B + (size_t)(bn*256 + srow)*1024 + scol;

    auto stageA = [&](int buf, int h, int t1) {
        size_t ko = (size_t)t1 * 64;
        #pragma unroll
        for (int q = 0; q < 2; q++)
            gload16(gA + (size_t)(h*128 + q*64)*1024 + ko,
                    &As[buf][(h*128 + q*64 + w*8)*64]);
    };
    auto stageB = [&](int buf, int h, int t1) {
        size_t ko = (size_t)t1 * 64;
        #pragma unroll
        for (int q = 0; q < 2; q++)
            gload16(gB + (size_t)(h*128 + q*64)*1024 + ko,
                    &Bs[buf][(h*128 + q*64 + w*8)*64]);
    };

    f32x4 acc[8][4];
    #pragma unroll
    for (int i = 0; i < 8; i++)
        #pragma unroll
        for (int j = 0; j < 4; j++)
            acc[i][j] = (f32x4){0.f, 0.f, 0.f, 0.f};

    constexpr int NT = 16;              // K/64
    stageA(0, 0, 0); stageB(0, 0, 0); stageA(0, 1, 0); stageB(0, 1, 0);

    const int rsw = (lm & 7);           // read-side swizzle key (row&7 == lm&7)
    for (int t = 0; t < NT; ++t) {
        const int cur = t & 1;
        const bool more = (t + 1 < NT);
        #pragma unroll
        for (int p = 0; p < 4; ++p) {
            if (more) {
                if (p == 0)      stageA(cur ^ 1, 0, t + 1);
                else if (p == 1) stageB(cur ^ 1, 0, t + 1);
                else if (p == 2) stageA(cur ^ 1, 1, t + 1);
                else             stageB(cur ^ 1, 1, t + 1);
            }
            if (p == 0) { if (more) wait_vm<6>(); else wait_vm<4>(); }
            if (p == 1) { if (more) wait_vm<4>(); else wait_vm<0>(); }
            barrier_raw();
            const int rh = p >> 1, ch = p & 1;
            frag8 af[4][2], bfr[2][2];
            #pragma unroll
            for (int i = 0; i < 4; i++)
                #pragma unroll
                for (int kk = 0; kk < 2; kk++)
                    af[i][kk] = *(frag8*)&As[cur][(wm + rh*64 + i*16 + lm)*64
                                      + (((kk*4 + quad) ^ rsw) * 8)];
            #pragma unroll
            for (int j = 0; j < 2; j++)
                #pragma unroll
                for (int kk = 0; kk < 2; kk++)
                    bfr[j][kk] = *(frag8*)&Bs[cur][(wn + ch*32 + j*16 + lm)*64
                                      + (((kk*4 + quad) ^ rsw) * 8)];
            __builtin_amdgcn_s_setprio(1);
            #pragma unroll
            for (int kk = 0; kk < 2; kk++)
                #pragma unroll
                for (int i = 0; i < 4; i++)
                    #pragma unroll
                    for (int j = 0; j < 2; j++)
                        acc[rh*4 + i][ch*2 + j] =
                            __builtin_amdgcn_mfma_f32_16x16x32_bf16(
                                af[i][kk], bfr[j][kk], acc[rh*4 + i][ch*2 + j],
                                0, 0, 0);
            __builtin_amdgcn_s_setprio(0);
        }
    }

    #pragma unroll
    for (int I = 0; I < 8; I++) {
        #pragma unroll
        for (int J = 0; J < 4; J++) {
            const int gcol = bn*256 + wn + (J >> 1)*32 + (J & 1)*16 + lm;
            #pragma unroll
            for (int r = 0; r < 4; r++) {
                const int grow = bm*256 + wm + (I >> 2)*64 + (I & 3)*16
                               + quad*4 + r;
                float vv = fmaxf(acc[I][J][r], 0.f);
                C[(size_t)grow * FFD + gcol] = f2bf(vv * vv);
            }
        }
    }
}

// ---------------------------------------------------------------------------
// qkvm GEMM, 8-wave 256x256 phase-split + T2 swizzle (fc8 template, R14-
// proven; same K=1024/lda=1024 staging). 13 n-tiles: 0..3 q, 4..7 k,
// 8..11 v (bf16 out, col base (bn&3)*256), 12 meta (relu(x@Wm1^T+bm1),
// f32 out, 256 cols). Grid 208 = 16 x 13. K-accum order identical to the
// 2-phase version (bit-identical outputs).
// ---------------------------------------------------------------------------
__global__ __launch_bounds__(512)
void gemm_qkvm8(const u16* __restrict__ xb,
                const u16* __restrict__ Wqb, const u16* __restrict__ Wkb,
                const u16* __restrict__ Wvb, const u16* __restrict__ Wm1b,
                const void* __restrict__ bm1,
                u16* __restrict__ q, u16* __restrict__ k, u16* __restrict__ v,
                float* __restrict__ hid, const u32* __restrict__ flags)
{
    __shared__ u16 As[2][256 * 64];
    __shared__ u16 Bs[2][256 * 64];
    const int tid = threadIdx.x;
    int bm, bn;
    xcd_map(blockIdx.x, 208, 13, bm, bn);

    const int bsel = (bn < 12) ? (bn >> 2) : 3;     // 0 q, 1 k, 2 v, 3 meta
    const int bcol = (bn < 12) ? (bn & 3) * 256 : 0;
    const u16* Bp = (bsel == 0) ? Wqb : (bsel == 1) ? Wkb
                  : (bsel == 2) ? Wvb : Wm1b;

    const int w = tid >> 6, lane = tid & 63;
    const int lm = lane & 15, quad = lane >> 4;
    const int wm = (w >> 2) * 128, wn = (w & 3) * 64;

    const int srow = tid >> 3;          // 0..63
    const int scol = (((tid & 7) ^ ((tid >> 3) & 7))) * 8;   // T2 pre-swizzle
    const u16* gA = xb + (size_t)(bm*256 + srow)*1024 + scol;
    const u16* gB = Bp + (size_t)(bcol + srow)*1024 + scol;

    auto stageA = [&](int buf, int h, int t1) {
        size_t ko = (size_t)t1 * 64;
        #pragma unroll
        for (int qq = 0; qq < 2; qq++)
            gload16(gA + (size_t)(h*128 + qq*64)*1024 + ko,
                    &As[buf][(h*128 + qq*64 + w*8)*64]);
    };
    auto stageB = [&](int buf, int h, int t1) {
        size_t ko = (size_t)t1 * 64;
        #pragma unroll
        for (int qq = 0; qq < 2; qq++)
            gload16(gB + (size_t)(h*128 + qq*64)*1024 + ko,
                    &Bs[buf][(h*128 + qq*64 + w*8)*64]);
    };

    f32x4 acc[8][4];
    #pragma unroll
    for (int i = 0; i < 8; i++)
        #pragma unroll
        for (int j = 0; j < 4; j++)
            acc[i][j] = (f32x4){0.f, 0.f, 0.f, 0.f};

    constexpr int NT = 16;              // K/64
    stageA(0, 0, 0); stageB(0, 0, 0); stageA(0, 1, 0); stageB(0, 1, 0);

    const int rsw = (lm & 7);
    for (int t = 0; t < NT; ++t) {
        const int cur = t & 1;
        const bool more = (t + 1 < NT);
        #pragma unroll
        for (int p = 0; p < 4; ++p) {
            if (more) {
                if (p == 0)      stageA(cur ^ 1, 0, t + 1);
                else if (p == 1) stageB(cur ^ 1, 0, t + 1);
                else if (p == 2) stageA(cur ^ 1, 1, t + 1);
                else             stageB(cur ^ 1, 1, t + 1);
            }
            if (p == 0) { if (more) wait_vm<6>(); else wait_vm<4>(); }
            if (p == 1) { if (more) wait_vm<4>(); else wait_vm<0>(); }
            barrier_raw();
            const int rh = p >> 1, ch = p & 1;
            frag8 af[4][2], bfr[2][2];
            #pragma unroll
            for (int i = 0; i < 4; i++)
                #pragma unroll
                for (int kk = 0; kk < 2; kk++)
                    af[i][kk] = *(frag8*)&As[cur][(wm + rh*64 + i*16 + lm)*64
                                      + (((kk*4 + quad) ^ rsw) * 8)];
            #pragma unroll
            for (int j = 0; j < 2; j++)
                #pragma unroll
                for (int kk = 0; kk < 2; kk++)
                    bfr[j][kk] = *(frag8*)&Bs[cur][(wn + ch*32 + j*16 + lm)*64
                                      + (((kk*4 + quad) ^ rsw) * 8)];
            __builtin_amdgcn_s_setprio(1);
            #pragma unroll
            for (int kk = 0; kk < 2; kk++)
                #pragma unroll
                for (int i = 0; i < 4; i++)
                    #pragma unroll
                    for (int j = 0; j < 2; j++)
                        acc[rh*4 + i][ch*2 + j] =
                            __builtin_amdgcn_mfma_f32_16x16x32_bf16(
                                af[i][kk], bfr[j][kk], acc[rh*4 + i][ch*2 + j],
                                0, 0, 0);
            __builtin_amdgcn_s_setprio(0);
        }
    }

    if (bsel < 3) {
        u16* outp = (bsel == 0) ? q : (bsel == 1) ? k : v;
        #pragma unroll
        for (int I = 0; I < 8; I++) {
            #pragma unroll
            for (int J = 0; J < 4; J++) {
                const int gcol = bcol + wn + (J >> 1)*32 + (J & 1)*16 + lm;
                #pragma unroll
                for (int r = 0; r < 4; r++) {
                    const int grow = bm*256 + wm + (I >> 2)*64 + (I & 3)*16
                                   + quad*4 + r;
                    outp[(size_t)grow * CC + gcol] = f2bf(acc[I][J][r]);
                }
            }
        }
    } else {
        const bool biasf = is_f32(flags, 5);
        #pragma unroll
        for (int I = 0; I < 8; I++) {
            #pragma unroll
            for (int J = 0; J < 4; J++) {
                const int gcol = wn + (J >> 1)*32 + (J & 1)*16 + lm;  // 0..255
                float bia = biasf ? ((const float*)bm1)[gcol]
                                  : bf2f(((const u16*)bm1)[gcol]);
                #pragma unroll
                for (int r = 0; r < 4; r++) {
                    const int grow = bm*256 + wm + (I >> 2)*64 + (I & 3)*16
                                   + quad*4 + r;
                    hid[(size_t)grow * HID + gcol] =
                        fmaxf(acc[I][J][r] + bia, 0.f);
                }
            }
        }
    }
}

// ---------------------------------------------------------------------------
// meta2 (unchanged)
// ---------------------------------------------------------------------------
__global__ __launch_bounds__(256)
void meta2_kernel(const float* __restrict__ hid, const void* __restrict__ Wm2,
                  const void* __restrict__ bm2, float* __restrict__ g,
                  float* __restrict__ dec, const u32* __restrict__ flags)
{
    const bool wf = is_f32(flags, 6);
    const bool bf = is_f32(flags, 7);
    __shared__ float hs[16][257];
    __shared__ float wsm[16][257];
    int tid  = threadIdx.x;
    int tok0 = blockIdx.x * 16;
    for (int i = tid; i < 16*256; i += 256) {
        wsm[i >> 8][i & 255] = wf ? ((const float*)Wm2)[i] : bf2f(((const u16*)Wm2)[i]);
        hs [i >> 8][i & 255] = hid[(size_t)tok0*256 + i];
    }
    __syncthreads();
    int tok = tid >> 4, hh = tid & 15;
    float s = 0.f;
    #pragma unroll 8
    for (int kk = 0; kk < 256; kk++) s = fmaf(hs[tok][kk], wsm[hh][kk], s);
    s += bf ? ((const float*)bm2)[hh] : bf2f(((const u16*)bm2)[hh]);
    float sg = 1.f / (1.f + expf(-s));
    int idx = (tok0 + tok) * HH + hh;
    g[idx]   = sg;
    dec[idx] = 1.f - sg;
}

// wave-parallel inclusive prefix sum of log(dec) over 64 chunk-steps
__device__ __forceinline__ void cum_prefix(const float* dd, float* cum, int tid)
{
    if (tid < 64) {
        float lw = logf(fmaxf(dd[tid], 1e-30f));
        #pragma unroll
        for (int off = 1; off < 64; off <<= 1) {
            float nv = __shfl_up(lw, off, 64);
            if (tid >= off) lw += nv;
        }
        cum[tid] = lw;
    }
    __syncthreads();
}

// ---------------------------------------------------------------------------
// scan pass 1 — MFMA version (R12-proven)
// ---------------------------------------------------------------------------
__global__ __launch_bounds__(256)
void scan_pass1(const u16* __restrict__ kbuf, const u16* __restrict__ vbuf,
                const float* __restrict__ g, const float* __restrict__ dec,
                float* __restrict__ Mb, float* __restrict__ Pb)
{
    __shared__ u16 kt[64*72];     // A: rows d, cols s (sw-scaled bf16)
    __shared__ u16 vt[64*72];     // B: rows e, cols s
    __shared__ float dd[64], gg[64], cum[64], sw[64];
    int tid = threadIdx.x;
    int bhc = blockIdx.x;
    int c = bhc & 31, h = (bhc >> 5) & 15, b = bhc >> 9;
    int t0 = c * CT;
    size_t rowbase = ((size_t)(b*TT + t0))*CC + h*DD;

    if (tid < 64) {
        int gidx = (b*TT + t0 + tid)*HH + h;
        dd[tid] = dec[gidx];
        gg[tid] = g[gidx];
    }
    __syncthreads();
    cum_prefix(dd, cum, tid);
    float ctot = cum[63];
    if (tid < 64) sw[tid] = gg[tid] * expf(ctot - cum[tid]);
    __syncthreads();

    #pragma unroll 4
    for (int i = tid; i < 4096; i += 256) {
        int ss = i >> 6, d = i & 63;
        size_t gi = rowbase + (size_t)ss*CC + d;
        kt[d*72 + ss] = f2bf(sw[ss] * bf2f(kbuf[gi]));
        vt[d*72 + ss] = vbuf[gi];          // d plays the e role here
    }
    __syncthreads();

    const int w = tid >> 6, lane = tid & 63;
    const int lm = lane & 15, quad = lane >> 4;

    f32x4 mf[4];
    #pragma unroll
    for (int j = 0; j < 4; j++) mf[j] = (f32x4){0.f,0.f,0.f,0.f};
    #pragma unroll
    for (int kk = 0; kk < 2; kk++) {
        frag8 aK = *(frag8*)&kt[(w*16 + lm)*72 + kk*32 + quad*8];
        #pragma unroll
        for (int j = 0; j < 4; j++) {
            frag8 bV = *(frag8*)&vt[(j*16 + lm)*72 + kk*32 + quad*8];
            mf[j] = __builtin_amdgcn_mfma_f32_16x16x32_bf16(aK, bV, mf[j], 0, 0, 0);
        }
    }

    size_t base = (size_t)bhc * 4096;
    #pragma unroll
    for (int r = 0; r < 4; r++) {
        int d = w*16 + quad*4 + r;
        #pragma unroll
        for (int j = 0; j < 4; j++)
            Mb[base + (size_t)d*64 + j*16 + lm] = mf[j][r];
    }
    if (tid == 0) Pb[bhc] = expf(ctot);
}

// ---------------------------------------------------------------------------
// scan pass 2 (unchanged)
// ---------------------------------------------------------------------------
__global__ __launch_bounds__(256)
void scan_pass2(float* __restrict__ MS, const float* __restrict__ Pb)
{
    int bh = blockIdx.x >> 4, grp = blockIdx.x & 15, tid = threadIdx.x;
    int eo = grp*256 + tid;
    float st = 0.f;
    for (int c = 0; c < NC; c++) {
        size_t e = ((size_t)bh*NC + c) * 4096 + eo;
        float p = Pb[bh*NC + c];
        float m = MS[e];
        MS[e] = st;
        st = fmaf(p, st, m);
    }
}

// ---------------------------------------------------------------------------
// fused scan pass 3 — MFMA version (R10-proven)
// ---------------------------------------------------------------------------
__global__ __launch_bounds__(256)
void scan_pass3(const u16* __restrict__ qbuf, const u16* __restrict__ kbuf,
                const u16* __restrict__ vbuf, const float* __restrict__ g,
                const float* __restrict__ dec, const float* __restrict__ Sb,
                u16* __restrict__ y)
{
    __shared__ u16 qs16[64*72];    // q rows t, cols d
    __shared__ u16 ks16[64*72];    // k rows s, cols d
    __shared__ u16 vt16[64*72];    // v^T rows e, cols s
    __shared__ u16 aws16[64*72];   // Aws rows t, cols s
    __shared__ float Ss_t[64*68];  // S^T rows e, cols d
    __shared__ float dd[64], gg[64], cum[64];
    int tid = threadIdx.x;
    int bhc = blockIdx.x;
    int c = bhc & 31, h = (bhc >> 5) & 15, b = bhc >> 9;
    int t0 = c * CT;
    size_t rowbase = ((size_t)(b*TT + t0))*CC + h*DD;
    size_t sbase = (size_t)bhc * 4096;

    {
        int sr = tid >> 2, d0 = (tid & 3) * 16;
        size_t gq = rowbase + (size_t)sr*CC + d0;
        *(uint4*)&qs16[sr*72 + d0]     = *(const uint4*)&qbuf[gq];
        *(uint4*)&qs16[sr*72 + d0 + 8] = *(const uint4*)&qbuf[gq + 8];
        *(uint4*)&ks16[sr*72 + d0]     = *(const uint4*)&kbuf[gq];
        *(uint4*)&ks16[sr*72 + d0 + 8] = *(const uint4*)&kbuf[gq + 8];
        #pragma unroll 4
        for (int i = tid; i < 4096; i += 256) {
            int ss = i >> 6, e = i & 63;
            vt16[e*72 + ss] = vbuf[rowbase + (size_t)ss*CC + e];
        }
        int dr = tid >> 2, e0 = (tid & 3) * 16;
        #pragma unroll
        for (int m = 0; m < 4; m++) {
            float4 sv4 = *(const float4*)&Sb[sbase + (size_t)dr*64 + e0 + m*4];
            Ss_t[(e0 + m*4 + 0)*68 + dr] = sv4.x;
            Ss_t[(e0 + m*4 + 1)*68 + dr] = sv4.y;
            Ss_t[(e0 + m*4 + 2)*68 + dr] = sv4.z;
            Ss_t[(e0 + m*4 + 3)*68 + dr] = sv4.w;
        }
        if (tid < 64) {
            int gidx = (b*TT + t0 + tid)*HH + h;
            dd[tid] = dec[gidx];
            gg[tid] = g[gidx];
        }
    }
    __syncthreads();
    cum_prefix(dd, cum, tid);

    const int w = tid >> 6, lane = tid & 63;
    const int lm = lane & 15, quad = lane >> 4;

    f32x4 a1f[4];
    #pragma unroll
    for (int j = 0; j < 4; j++) a1f[j] = (f32x4){0.f,0.f,0.f,0.f};
    #pragma unroll
    for (int kk = 0; kk < 2; kk++) {
        frag8 aq = *(frag8*)&qs16[(w*16 + lm)*72 + kk*32 + quad*8];
        #pragma unroll
        for (int j = 0; j < 4; j++) {
            frag8 bk = *(frag8*)&ks16[(j*16 + lm)*72 + kk*32 + quad*8];
            a1f[j] = __builtin_amdgcn_mfma_f32_16x16x32_bf16(aq, bk, a1f[j], 0, 0, 0);
        }
    }

    #pragma unroll
    for (int j = 0; j < 4; j++) {
        #pragma unroll
        for (int r = 0; r < 4; r++) {
            int t = w*16 + quad*4 + r, s = j*16 + lm;
            float wgt = (s <= t) ? gg[s] * expf(cum[t] - cum[s]) : 0.f;
            aws16[t*72 + s] = f2bf(wgt * a1f[j][r]);
        }
    }
    __syncthreads();

    f32x4 of[4];
    #pragma unroll
    for (int j = 0; j < 4; j++) of[j] = (f32x4){0.f,0.f,0.f,0.f};
    #pragma unroll
    for (int kk = 0; kk < 2; kk++) {
        frag8 aA = *(frag8*)&aws16[(w*16 + lm)*72 + kk*32 + quad*8];
        #pragma unroll
        for (int j = 0; j < 4; j++) {
            frag8 bV = *(frag8*)&vt16[(j*16 + lm)*72 + kk*32 + quad*8];
            of[j] = __builtin_amdgcn_mfma_f32_16x16x32_bf16(aA, bV, of[j], 0, 0, 0);
        }
    }

    float o2v[4][4] = {};          // [j][r]
    for (int d8 = 0; d8 < 8; d8++) {
        frag8 qr[4];
        #pragma unroll
        for (int r = 0; r < 4; r++)
            qr[r] = *(frag8*)&qs16[(w*16 + quad*4 + r)*72 + d8*8];
        float qv[4][8];
        #pragma unroll
        for (int r = 0; r < 4; r++)
            #pragma unroll
            for (int d2 = 0; d2 < 8; d2++)
                qv[r][d2] = bf2f((u16)qr[r][d2]);
        #pragma unroll
        for (int j = 0; j < 4; j++) {
            int e = j*16 + lm;
            float4 s0 = *(float4*)&Ss_t[e*68 + d8*8];
            float4 s1 = *(float4*)&Ss_t[e*68 + d8*8 + 4];
            float sv[8] = {s0.x, s0.y, s0.z, s0.w, s1.x, s1.y, s1.z, s1.w};
            #pragma unroll
            for (int d2 = 0; d2 < 8; d2++)
                #pragma unroll
                for (int r = 0; r < 4; r++)
                    o2v[j][r] = fmaf(qv[r][d2], sv[d2], o2v[j][r]);
        }
    }

    #pragma unroll
    for (int r = 0; r < 4; r++) {
        int t = w*16 + quad*4 + r;
        float cd = expf(cum[t]);
        size_t obase = rowbase + (size_t)t*CC;
        #pragma unroll
        for (int j = 0; j < 4; j++)
            y[obase + j*16 + lm] = f2bf(fmaf(cd, o2v[j][r], of[j][r]));
    }
}

// ---------------------------------------------------------------------------
// rmsnorm v3 (unchanged)
// ---------------------------------------------------------------------------
__global__ __launch_bounds__(256)
void rmsnorm_kernel(const float* __restrict__ p0, const float* __restrict__ p1,
                    void* __restrict__ yres, u16* __restrict__ yn,
                    const u32* __restrict__ flags)
{
    const bool of32 = flags[0] != 0;
    __shared__ float red[4];
    __shared__ float sscale;
    int row = blockIdx.x, tid = threadIdx.x;
    size_t base = (size_t)row*CC + tid*4;
    float4 a = *(const float4*)&p0[base];
    float4 b = *(const float4*)&p1[base];
    float v0 = a.x + b.x, v1 = a.y + b.y, v2 = a.z + b.z, v3 = a.w + b.w;
    if (of32) {
        *(float4*)((float*)yres + base) = make_float4(v0, v1, v2, v3);
    } else {
        u16* yr = (u16*)yres + base;
        yr[0] = f2bf(v0); yr[1] = f2bf(v1); yr[2] = f2bf(v2); yr[3] = f2bf(v3);
    }
    float p = v0*v0 + v1*v1 + v2*v2 + v3*v3;
    #pragma unroll
    for (int off = 32; off > 0; off >>= 1) p += __shfl_down(p, off, 64);
    if ((tid & 63) == 0) red[tid >> 6] = p;
    __syncthreads();
    if (tid == 0) {
        float tot = red[0] + red[1] + red[2] + red[3];
        sscale = rsqrtf(tot * (1.0f/1024.0f) + 1.1920928955078125e-07f);
    }
    __syncthreads();
    float sc = sscale;
    yn[base + 0] = f2bf(v0 * sc);
    yn[base + 1] = f2bf(v1 * sc);
    yn[base + 2] = f2bf(v2 * sc);
    yn[base + 3] = f2bf(v3 * sc);
}

// ---------------------------------------------------------------------------
// Workspace layout (peak 48 MB + 64 B, phase-aliased; residual lives in d_out)
// ---------------------------------------------------------------------------
extern "C" void kernel_launch(void* const* d_in, const int* in_sizes, int n_in,
                              void* d_out, int out_size, void* d_ws, size_t ws_size,
                              hipStream_t stream)
{
    char* ws = (char*)d_ws;
    u16*   xb     = (u16*)  (ws + 32*MB);
    u16*   Wqb    = (u16*)  (ws + 40*MB);
    u16*   Wkb    = (u16*)  (ws + 42*MB);
    u16*   Wvb    = (u16*)  (ws + 44*MB);
    u16*   Wm1b   = (u16*)  (ws + 46*MB);
    u16*   Wprojb = (u16*)  (ws + 8*MB);
    u16*   q      = (u16*)  (ws + 0*MB);
    u16*   k      = (u16*)  (ws + 16*MB);
    u16*   v      = (u16*)  (ws + 24*MB);
    float* hid    = (float*)(ws + 10*MB);
    float* g      = (float*)(ws + 14*MB);
    float* dec    = (float*)(ws + 14*MB + 262144);
    float* Pb     = (float*)(ws + 14*MB + 524288);
    float* MS     = (float*)(ws + 32*MB);
    u16*   yat    = q;                      // pass3 writes over q (exact alias)
    float* p0     = (float*)(ws + 16*MB);   // over k,v after scan3
    float* p1     = (float*)(ws + 32*MB);   // over MS after scan3
    u16*   yn     = (u16*)  (ws + 0*MB);    // over yat after proj
    u16*   Wfcb   = (u16*)  (ws + 8*MB);    // over Wprojb/hid/g after proj
    u16*   h1     = (u16*)  (ws + 16*MB);   // over p0,p1 after rmsnorm
    u16*   Wcpb   = (u16*)  (ws + 0*MB);    // over yn after fc
    u32*   flags  = (u32*)  (ws + 48*MB);

    InPtrs ip;
    for (int i = 0; i < 11; i++) { ip.p[i] = d_in[i]; ip.n[i] = in_sizes[i]; }
    sniff_kernel<<<1, 64, 0, stream>>>(ip, flags);

    // conv1: x, Wq, Wk, Wv, Wm1, Wproj -> bf16
    ConvArgs c1{};
    c1.src[0] = d_in[0]; c1.dst[0] = xb;     c1.flag[0] = 0;
    c1.src[1] = d_in[1]; c1.dst[1] = Wqb;    c1.flag[1] = 1;
    c1.src[2] = d_in[2]; c1.dst[2] = Wkb;    c1.flag[2] = 2;
    c1.src[3] = d_in[3]; c1.dst[3] = Wvb;    c1.flag[3] = 3;
    c1.src[4] = d_in[4]; c1.dst[4] = Wm1b;   c1.flag[4] = 4;
    c1.src[5] = d_in[8]; c1.dst[5] = Wprojb; c1.flag[5] = 8;
    {
        int nb[6] = {2048, 512, 512, 512, 128, 512};
        int cum = 0;
        for (int i = 0; i < 6; i++) { c1.bstart[i] = cum; cum += nb[i]; }
        c1.bstart[6] = cum;
        c1.nseg = 6;
        conv_kernel<<<cum, 256, 0, stream>>>(c1, flags);
    }

    // fused qkv + meta1: 8-wave 256^2 phase-split + T2 swizzle (fc8 template)
    gemm_qkvm8<<<208, 512, 0, stream>>>(xb, Wqb, Wkb, Wvb, Wm1b, d_in[5],
                                        q, k, v, hid, flags);
    meta2_kernel<<<NTOK/16, 256, 0, stream>>>(hid, d_in[6], d_in[7], g, dec, flags);
    // chunked gated linear-attention scan
    scan_pass1<<<NCHK, 256, 0, stream>>>(k, v, g, dec, MS, Pb);
    scan_pass2<<<NBH*16, 256, 0, stream>>>(MS, Pb);
    scan_pass3<<<NCHK, 256, 0, stream>>>(q, k, v, g, dec, MS, yat);
    // proj: split-K x2 -> f32 partials p0,p1 (proven 128x128 config)
    gemm_nt<0,128,128,1><<<dim3(256, 2), 256, 0, stream>>>(yat, Wprojb, p0, p1,
        nullptr, NTOK, CC, 512, CC, CC, flags, -2);
    // conv2: Wfc -> bf16 (region free after proj)
    ConvArgs c2{};
    c2.src[0] = d_in[9]; c2.dst[0] = Wfcb; c2.flag[0] = 9;
    c2.bstart[0] = 0; for (int i = 1; i < 7; i++) c2.bstart[i] = 2048;
    c2.nseg = 1;
    conv_kernel<<<2048, 256, 0, stream>>>(c2, flags);
    // rmsnorm: combine partials, residual -> d_out, normed -> yn
    rmsnorm_kernel<<<NTOK, 256, 0, stream>>>(p0, p1, d_out, yn, flags);
    // squared-relu MLP: 8-wave 256^2 phase-split + T2 swizzle (R14-proven)
    gemm_fc8<<<256, 512, 0, stream>>>(yn, Wfcb, h1);
    // conv3: Wcp -> bf16 (over yn, free after fc)
    ConvArgs c3{};
    c3.src[0] = d_in[10]; c3.dst[0] = Wcpb; c3.flag[0] = 10;
    c3.bstart[0] = 0; for (int i = 1; i < 7; i++) c3.bstart[i] = 2048;
    c3.nseg = 1;
    conv_kernel<<<2048, 256, 0, stream>>>(c3, flags);
    // final: out = residual(d_out) + h1 @ Wcp^T
    // R6-proven best: 64x64 tile, BK=64, 1024 blocks = 4/CU
    gemm_nt<3,64,64,2><<<dim3(1024, 1), 256, 0, stream>>>(h1, Wcpb, d_out, nullptr,
        d_out, NTOK, CC, FFD, FFD, FFD, flags, 0);
}